// Round 22
// baseline (734.766 us; speedup 1.0000x reference)
//
#include <hip/hip_runtime.h>
#include <stdint.h>
#include <math.h>

#define TTOK 8192
#define DDIM 1024
#define FDIM 4096
#define NEXP 8
#define NASG (TTOK*2)
#define MAXTILES 136   // sum ceil(n_e/128) <= 128 + 7

typedef __attribute__((ext_vector_type(8))) short bf16x8;
typedef __attribute__((ext_vector_type(4))) float f32x4;
typedef __attribute__((ext_vector_type(4))) float f4v;
typedef __attribute__((ext_vector_type(4))) unsigned short u16x4;
typedef __attribute__((ext_vector_type(8))) unsigned short u16x8;

__device__ __forceinline__ unsigned short f2bf(float f) {
  union { float f; unsigned int u; } v; v.f = f;
  unsigned int u = v.u;
  u += 0x7fffu + ((u >> 16) & 1u);   // round-to-nearest-even
  return (unsigned short)(u >> 16);
}

__device__ __forceinline__ float bf2f(unsigned short s) {
  union { unsigned int u; float f; } v; v.u = (unsigned int)s << 16;
  return v.f;
}

__device__ __forceinline__ void gload16(const void* g, void* l) {
  __builtin_amdgcn_global_load_lds(
    (__attribute__((address_space(1))) unsigned int*)(uintptr_t)g,
    (__attribute__((address_space(3))) unsigned int*)(uintptr_t)l,
    16, 0, 0);
}

// ------ router: one wave per token, fp64 accumulate, vectorized loads ------
__global__ __launch_bounds__(256) void router_kernel(
    const float* __restrict__ x, const float* __restrict__ rw,
    const float* __restrict__ rb, int* __restrict__ topi,
    float* __restrict__ topw, int* __restrict__ counts,
    unsigned short* __restrict__ xb)
{
  int wave = threadIdx.x >> 6;
  int lane = threadIdx.x & 63;
  int t = blockIdx.x * 4 + wave;
  if (t >= TTOK) return;
  double acc[8];
#pragma unroll
  for (int e = 0; e < 8; e++) acc[e] = 0.0;
  const float* xr = x + (size_t)t * DDIM;
  unsigned short* xbr = xb + (size_t)t * DDIM;
#pragma unroll
  for (int i = 0; i < DDIM/256; i++) {
    int d4 = i*256 + lane*4;
    f4v xv4 = __builtin_nontemporal_load((const f4v*)(xr + d4));  // read-once
    u16x4 ov;
    ov[0] = f2bf(xv4[0]); ov[1] = f2bf(xv4[1]);
    ov[2] = f2bf(xv4[2]); ov[3] = f2bf(xv4[3]);
    *(u16x4*)(xbr + d4) = ov;
#pragma unroll
    for (int j = 0; j < 4; j++) {
      double xv = (double)xv4[j];
      const float* rwr = rw + (size_t)(d4 + j) * 8;
      f4v r0 = *(const f4v*)(rwr);
      f4v r1 = *(const f4v*)(rwr + 4);
      acc[0] += xv * (double)r0[0];
      acc[1] += xv * (double)r0[1];
      acc[2] += xv * (double)r0[2];
      acc[3] += xv * (double)r0[3];
      acc[4] += xv * (double)r1[0];
      acc[5] += xv * (double)r1[1];
      acc[6] += xv * (double)r1[2];
      acc[7] += xv * (double)r1[3];
    }
  }
#pragma unroll
  for (int e = 0; e < 8; e++) {
    for (int off = 32; off >= 1; off >>= 1)
      acc[e] += __shfl_xor(acc[e], off);
  }
  if (lane == 0) {
    float lg[8];
#pragma unroll
    for (int e = 0; e < 8; e++) lg[e] = (float)acc[e] + rb[e];
    int i0 = 0;
    for (int e = 1; e < 8; e++) if (lg[e] > lg[i0]) i0 = e;   // ties -> lowest idx
    int i1 = -1;
    for (int e = 0; e < 8; e++) {
      if (e == i0) continue;
      if (i1 < 0 || lg[e] > lg[i1]) i1 = e;
    }
    double z = exp((double)lg[i1] - (double)lg[i0]);
    float w0 = (float)(1.0 / (1.0 + z));
    topi[t*2]   = i0;  topi[t*2+1] = i1;
    topw[t*2]   = w0;  topw[t*2+1] = 1.0f - w0;
    atomicAdd(&counts[i0], 1);
    atomicAdd(&counts[i1], 1);
  }
}

// ---- transpose+convert, 128x128 tiles, XOR-swizzled 64KB LDS ----
// [E][R][C] f32 -> [E][C][R] bf16. 512B read segs, 256B write segs (u16x8).
// f32 source reads are NON-TEMPORAL (read-once) so the bf16 outputs stay
// resident in L3 for the immediately-following GEMMs.
__global__ __launch_bounds__(512) void transpose2_kernel(
    const float* __restrict__ w1, unsigned short* __restrict__ w1t,
    const float* __restrict__ w2, unsigned short* __restrict__ w2t)
{
  __shared__ float lds[128*128];   // 64 KB, swizzled: (r,c) at [r*128 + (c^(r&31))]
  const int perMat = (DDIM/128)*(FDIM/128);   // 256
  int b = blockIdx.x;
  const float* w; unsigned short* wt; int R, C;
  if (b < NEXP*perMat) { w = w1; wt = w1t; R = DDIM; C = FDIM; }
  else { b -= NEXP*perMat; w = w2; wt = w2t; R = FDIM; C = DDIM; }
  int tpr = C >> 7;
  int e = b / perMat;
  int rem = b - e*perMat;
  int tr = rem / tpr;
  int tc = rem - tr*tpr;
  int tid = threadIdx.x;
  size_t ibase = (size_t)e*R*C + (size_t)(tr*128)*C + (size_t)(tc*128);
  size_t obase = (size_t)e*R*C + (size_t)(tc*128)*R + (size_t)(tr*128);
  // phase 1: non-temporal float4 loads, 512B contiguous per 32 lanes
#pragma unroll
  for (int i = 0; i < 8; i++) {
    int s = tid + i*512;
    int r = s >> 5;
    int c4 = (s & 31) << 2;
    f4v v = __builtin_nontemporal_load((const f4v*)(w + ibase + (size_t)r*C + c4));
    int xr = r & 31;
#pragma unroll
    for (int j = 0; j < 4; j++)
      lds[r*128 + ((c4 + j) ^ xr)] = v[j];
  }
  __syncthreads();
  // phase 2: out[oc][r8..r8+7] via u16x8 (16B) stores, 256B per out-row group
#pragma unroll
  for (int i = 0; i < 4; i++) {
    int s = tid + i*512;
    int oc = s >> 4;
    int r8 = (s & 15) << 3;
    u16x8 o;
#pragma unroll
    for (int j = 0; j < 8; j++) {
      int r = r8 + j;
      o[j] = f2bf(lds[r*128 + (oc ^ (r & 31))]);
    }
    *(u16x8*)(wt + obase + (size_t)oc*R + r8) = o;
  }
}

// ------ counting sort + compact tile list (single block) ------
__global__ __launch_bounds__(256) void permbuild_kernel(
    const int* __restrict__ topi, const int* __restrict__ counts,
    int* __restrict__ offsets, int* __restrict__ perm, int* __restrict__ islot,
    int* __restrict__ tlist, int* __restrict__ tcount)
{
  __shared__ int hist[256 * 8];
  __shared__ int offs[NEXP + 1];
  int tid = threadIdx.x;
  if (tid == 0) {
    int s = 0;
    for (int e = 0; e < 8; e++) { offs[e] = s; s += counts[e]; }
    offs[8] = s;
    for (int e = 0; e <= 8; e++) offsets[e] = offs[e];
    int k = 0;
    for (int e = 0; e < 8; e++) {
      int m = (counts[e] + 127) >> 7;
      for (int r = 0; r < m; r++) tlist[k++] = (e << 8) | r;
    }
    tcount[0] = k;
  }
  int cnt[8];
#pragma unroll
  for (int e = 0; e < 8; e++) cnt[e] = 0;
  int base = tid * 64;
  for (int i = 0; i < 64; i++) cnt[topi[base + i]]++;
#pragma unroll
  for (int e = 0; e < 8; e++) hist[tid*8 + e] = cnt[e];
  __syncthreads();
  if (tid < 8) {
    int s = 0;
    for (int th = 0; th < 256; th++) { int v = hist[th*8 + tid]; hist[th*8 + tid] = s; s += v; }
  }
  __syncthreads();
  int pos[8];
#pragma unroll
  for (int e = 0; e < 8; e++) pos[e] = offs[e] + hist[tid*8 + e];
  for (int i = 0; i < 64; i++) {
    int a = base + i;
    int e = topi[a];
    int p = pos[e]++;
    perm[p] = a >> 1;
    islot[a] = p;
  }
}

// ========= 128x128 grouped GEMM, m97-faithful + compact tile list ==========
// r10-verbatim loop, linear decode (id%8 = nt%8 pins each B-panel to one
// XCD's L2 -- measured optimal; r20's regroup thrashed B).
// GELU=true epilogue: NON-TEMPORAL H stores (H is stream-once, 128MB; keeping
// it out of L3 preserves w1t residency during gemm1 and w2t for gemm2).
// NO __launch_bounds__ (r12) / NO atomics (r18).

template<int KDIM, int NDIM, bool GELU>
__global__ void gemm128(
    const unsigned short* __restrict__ Asrc,
    const unsigned short* __restrict__ Bsrc,
    const float* __restrict__ bias,
    const int* __restrict__ perm,
    const int* __restrict__ offsets,
    const int* __restrict__ tlist,
    const int* __restrict__ tcount,
    void* __restrict__ Cout)
{
  constexpr int KT = KDIM / 64;
  constexpr int NT = NDIM / 128;
  int b = blockIdx.x;
  int ti = b / NT;
  int nt = b - ti * NT;
  if (ti >= tcount[0]) return;
  int code = tlist[ti];
  int e = code >> 8;
  int rt = code & 255;
  int off = offsets[e];
  int n_e = offsets[e+1] - off;

  __shared__ __align__(16) unsigned short lds[2 * 128 * 64];   // 32 KiB
  char* ldsA = (char*)lds;            // A: 128 rows x 128B
  char* ldsB = (char*)lds + 16384;    // B: 128 rows x 128B

  int tid = threadIdx.x;
  int lane = tid & 63;
  int wid = tid >> 6;          // 0..3
  int wr = wid >> 1;           // 0..1 (M strip)
  int wc = wid & 1;            // 0..1 (N strip)
  int tb0 = (lane >> 4) * 16;
  int rA = wr*64 + (lane & 15);
  int rB = wc*64 + (lane & 15);
  int xa  = (rA & 7) << 4;
  int xbw = (rB & 7) << 4;
  int aks0 = rA*128 + ( tb0       ^ xa);
  int aks1 = rA*128 + ((64 + tb0) ^ xa);
  int bks0 = rB*128 + ( tb0       ^ xbw);
  int bks1 = rB*128 + ((64 + tb0) ^ xbw);

  // staging: 4 A-slots + 4 B-slots per thread (1024 slots = 128 rows x 8 chunks)
  const char* srcA[4];
  const char* srcB[4];
#pragma unroll
  for (int i = 0; i < 4; i++) {
    int slot = tid + i*256;
    int r = slot >> 3;
    int kc = (slot & 7) ^ (r & 7);   // inverse swizzle on global k-chunk
    int g = off + rt*128 + r;
    if (g > NASG-1) g = NASG-1;
    size_t ar = GELU ? (size_t)perm[g] : (size_t)g;
    srcA[i] = (const char*)Asrc + (ar * KDIM + (size_t)kc*8) * 2;
    int col = nt*128 + r;
    srcB[i] = (const char*)Bsrc + (((size_t)e*NDIM + col) * KDIM + (size_t)kc*8) * 2;
  }
  int dstOff = tid * 16;

  f32x4 acc[4][4];
#pragma unroll
  for (int m = 0; m < 4; m++)
#pragma unroll
    for (int n = 0; n < 4; n++) acc[m][n] = (f32x4){0.f,0.f,0.f,0.f};

#pragma unroll 1
  for (int kt = 0; kt < KT; ++kt) {
    __syncthreads();   // previous compute done before overwrite
#pragma unroll
    for (int i = 0; i < 4; i++) {
      gload16(srcA[i] + (size_t)kt*128, ldsA + dstOff + i*4096);
      gload16(srcB[i] + (size_t)kt*128, ldsB + dstOff + i*4096);
    }
    __syncthreads();   // compiler-inserted vmcnt(0) drain: tile ready
#pragma unroll
    for (int ks = 0; ks < 2; ks++) {
      int ao = ks ? aks1 : aks0;
      int bo = ks ? bks1 : bks0;
      bf16x8 a[4], bb[4];
#pragma unroll
      for (int mi = 0; mi < 4; mi++) a[mi]  = *(const bf16x8*)(ldsA + mi*2048 + ao);
#pragma unroll
      for (int ni = 0; ni < 4; ni++) bb[ni] = *(const bf16x8*)(ldsB + ni*2048 + bo);
#pragma unroll
      for (int mi = 0; mi < 4; mi++)
#pragma unroll
        for (int ni = 0; ni < 4; ni++)
          acc[mi][ni] = __builtin_amdgcn_mfma_f32_16x16x32_bf16(a[mi], bb[ni], acc[mi][ni], 0, 0, 0);
    }
  }

  // epilogue
  int rq = (lane >> 4) * 4;
  int lc = lane & 15;
  if (GELU) {
    unsigned short* H = (unsigned short*)Cout;
#pragma unroll
    for (int mi = 0; mi < 4; mi++)
#pragma unroll
      for (int j = 0; j < 4; j++) {
        int sl = rt*128 + wr*64 + mi*16 + rq + j;
        if (sl < n_e) {
          size_t hrow = (size_t)(off + sl) * NDIM;
#pragma unroll
          for (int ni = 0; ni < 4; ni++) {
            int col = nt*128 + wc*64 + ni*16 + lc;
            float v = acc[mi][ni][j] + bias[e*NDIM + col];
            float g = 0.5f * v * (1.0f + erff(v * 0.70710678118654752f));
            __builtin_nontemporal_store(f2bf(g), H + hrow + col);   // stream-once
          }
        }
      }
  } else {
    unsigned short* Y = (unsigned short*)Cout;   // bf16 partial outputs
#pragma unroll
    for (int mi = 0; mi < 4; mi++)
#pragma unroll
      for (int j = 0; j < 4; j++) {
        int sl = rt*128 + wr*64 + mi*16 + rq + j;
        if (sl < n_e) {
          size_t yrow = (size_t)(off + sl) * NDIM;
#pragma unroll
          for (int ni = 0; ni < 4; ni++) {
            int col = nt*128 + wc*64 + ni*16 + lc;
            Y[yrow + col] = f2bf(acc[mi][ni][j]);
          }
        }
      }
  }
}

// ---------- combine: out[t] = sum_k w_k * (Y[slot_k] + b2[e_k]) ----------
__global__ __launch_bounds__(256) void combine_kernel(
    const unsigned short* __restrict__ Y, const float* __restrict__ b2,
    const int* __restrict__ topi, const float* __restrict__ topw,
    const int* __restrict__ islot, float* __restrict__ out)
{
  int t = blockIdx.x;
  int s0 = islot[t*2], s1 = islot[t*2+1];
  int e0 = topi[t*2],  e1 = topi[t*2+1];
  float w0 = topw[t*2], w1 = topw[t*2+1];
  int d = threadIdx.x * 4;
  u16x4 y0 = *(const u16x4*)(Y + (size_t)s0*DDIM + d);
  u16x4 y1 = *(const u16x4*)(Y + (size_t)s1*DDIM + d);
  f4v c0 = *(const f4v*)(b2 + (size_t)e0*DDIM + d);
  f4v c1 = *(const f4v*)(b2 + (size_t)e1*DDIM + d);
  f4v o;
#pragma unroll
  for (int j = 0; j < 4; j++)
    o[j] = w0*(bf2f(y0[j]) + c0[j]) + w1*(bf2f(y1[j]) + c1[j]);
  *(f4v*)(out + (size_t)t*DDIM + d) = o;
}

extern "C" void kernel_launch(void* const* d_in, const int* in_sizes, int n_in,
                              void* d_out, int out_size, void* d_ws, size_t ws_size,
                              hipStream_t stream) {
  const float* x  = (const float*)d_in[0];
  const float* w1 = (const float*)d_in[1];
  const float* b1 = (const float*)d_in[2];
  const float* w2 = (const float*)d_in[3];
  const float* b2 = (const float*)d_in[4];
  const float* rw = (const float*)d_in[5];
  const float* rb = (const float*)d_in[6];
  float* out = (float*)d_out;

  char* p = (char*)d_ws;
  size_t o = 0;
  auto take = [&](size_t bytes) -> void* {
    void* r = p + o;
    o = (o + bytes + 255) & ~(size_t)255;
    return r;
  };
  int*            counts  = (int*)take(NEXP * 4);
  int*            offsets = (int*)take((NEXP + 1) * 4);
  int*            tlist   = (int*)take(MAXTILES * 4);
  int*            tcount  = (int*)take(4);
  int*            topi    = (int*)take((size_t)NASG * 4);
  float*          topw    = (float*)take((size_t)NASG * 4);
  int*            perm    = (int*)take((size_t)NASG * 4);
  int*            islot   = (int*)take((size_t)NASG * 4);
  unsigned short* w1t     = (unsigned short*)take((size_t)NEXP * FDIM * DDIM * 2);
  unsigned short* xb      = (unsigned short*)take((size_t)TTOK * DDIM * 2);
  unsigned short* w2t     = (unsigned short*)take((size_t)NEXP * DDIM * FDIM * 2);
  unsigned short* H       = (unsigned short*)take((size_t)NASG * FDIM * 2);
  // Y (bf16, 32 MiB) aliases w1t (dead after gemm1, 64 MiB)
  unsigned short* Y       = w1t;

  if (o > ws_size) {   // workspace insufficient: fail visibly (zeros)
    hipMemsetAsync(d_out, 0, (size_t)out_size * 4, stream);
    return;
  }

  hipMemsetAsync(counts, 0, NEXP * 4, stream);

  router_kernel<<<TTOK/4, 256, 0, stream>>>(x, rw, rb, topi, topw, counts, xb);
  transpose2_kernel<<<2*NEXP*(DDIM/128)*(FDIM/128), 512, 0, stream>>>(w1, w1t, w2, w2t);
  permbuild_kernel<<<1, 256, 0, stream>>>(topi, counts, offsets, perm, islot, tlist, tcount);
  gemm128<DDIM, FDIM, true ><<<(MAXTILES-1)*(FDIM/128), 256, 0, stream>>>(xb, w1t, b1, perm, offsets, tlist, tcount, (void*)H);
  gemm128<FDIM, DDIM, false><<<(MAXTILES-1)*(DDIM/128), 256, 0, stream>>>(H, w2t, nullptr, perm, offsets, tlist, tcount, (void*)Y);
  combine_kernel<<<TTOK, 256, 0, stream>>>(Y, b2, topi, topw, islot, out);
}

// Round 23
// 718.715 us; speedup vs baseline: 1.0223x; 1.0223x over previous
//
#include <hip/hip_runtime.h>
#include <stdint.h>
#include <math.h>

#define TTOK 8192
#define DDIM 1024
#define FDIM 4096
#define NEXP 8
#define NASG (TTOK*2)
#define MAXTILES 136   // sum ceil(n_e/128) <= 128 + 7

typedef __attribute__((ext_vector_type(8))) short bf16x8;
typedef __attribute__((ext_vector_type(4))) float f32x4;
typedef __attribute__((ext_vector_type(4))) float f4v;
typedef __attribute__((ext_vector_type(4))) unsigned short u16x4;
typedef __attribute__((ext_vector_type(8))) unsigned short u16x8;

__device__ __forceinline__ unsigned short f2bf(float f) {
  union { float f; unsigned int u; } v; v.f = f;
  unsigned int u = v.u;
  u += 0x7fffu + ((u >> 16) & 1u);   // round-to-nearest-even
  return (unsigned short)(u >> 16);
}

__device__ __forceinline__ float bf2f(unsigned short s) {
  union { unsigned int u; float f; } v; v.u = (unsigned int)s << 16;
  return v.f;
}

__device__ __forceinline__ void gload16(const void* g, void* l) {
  __builtin_amdgcn_global_load_lds(
    (__attribute__((address_space(1))) unsigned int*)(uintptr_t)g,
    (__attribute__((address_space(3))) unsigned int*)(uintptr_t)l,
    16, 0, 0);
}

// ------ router: one wave per token, fp64 accumulate, vectorized loads ------
__global__ __launch_bounds__(256) void router_kernel(
    const float* __restrict__ x, const float* __restrict__ rw,
    const float* __restrict__ rb, int* __restrict__ topi,
    float* __restrict__ topw, int* __restrict__ counts,
    unsigned short* __restrict__ xb)
{
  int wave = threadIdx.x >> 6;
  int lane = threadIdx.x & 63;
  int t = blockIdx.x * 4 + wave;
  if (t >= TTOK) return;
  double acc[8];
#pragma unroll
  for (int e = 0; e < 8; e++) acc[e] = 0.0;
  const float* xr = x + (size_t)t * DDIM;
  unsigned short* xbr = xb + (size_t)t * DDIM;
#pragma unroll
  for (int i = 0; i < DDIM/256; i++) {
    int d4 = i*256 + lane*4;
    f4v xv4 = __builtin_nontemporal_load((const f4v*)(xr + d4));  // read-once
    u16x4 ov;
    ov[0] = f2bf(xv4[0]); ov[1] = f2bf(xv4[1]);
    ov[2] = f2bf(xv4[2]); ov[3] = f2bf(xv4[3]);
    *(u16x4*)(xbr + d4) = ov;
#pragma unroll
    for (int j = 0; j < 4; j++) {
      double xv = (double)xv4[j];
      const float* rwr = rw + (size_t)(d4 + j) * 8;
      f4v r0 = *(const f4v*)(rwr);
      f4v r1 = *(const f4v*)(rwr + 4);
      acc[0] += xv * (double)r0[0];
      acc[1] += xv * (double)r0[1];
      acc[2] += xv * (double)r0[2];
      acc[3] += xv * (double)r0[3];
      acc[4] += xv * (double)r1[0];
      acc[5] += xv * (double)r1[1];
      acc[6] += xv * (double)r1[2];
      acc[7] += xv * (double)r1[3];
    }
  }
#pragma unroll
  for (int e = 0; e < 8; e++) {
    for (int off = 32; off >= 1; off >>= 1)
      acc[e] += __shfl_xor(acc[e], off);
  }
  if (lane == 0) {
    float lg[8];
#pragma unroll
    for (int e = 0; e < 8; e++) lg[e] = (float)acc[e] + rb[e];
    int i0 = 0;
    for (int e = 1; e < 8; e++) if (lg[e] > lg[i0]) i0 = e;   // ties -> lowest idx
    int i1 = -1;
    for (int e = 0; e < 8; e++) {
      if (e == i0) continue;
      if (i1 < 0 || lg[e] > lg[i1]) i1 = e;
    }
    double z = exp((double)lg[i1] - (double)lg[i0]);
    float w0 = (float)(1.0 / (1.0 + z));
    topi[t*2]   = i0;  topi[t*2+1] = i1;
    topw[t*2]   = w0;  topw[t*2+1] = 1.0f - w0;
    atomicAdd(&counts[i0], 1);
    atomicAdd(&counts[i1], 1);
  }
}

// ---- transpose+convert, 128x128 tiles, XOR-swizzled 64KB LDS ----
// [E][R][C] f32 -> [E][C][R] bf16. 512B read segs, 256B write segs (u16x8).
// f32 source reads are NON-TEMPORAL (read-once) so the bf16 outputs stay
// resident in L3 for the immediately-following GEMMs (measured: -27us/gemm).
__global__ __launch_bounds__(512) void transpose2_kernel(
    const float* __restrict__ w1, unsigned short* __restrict__ w1t,
    const float* __restrict__ w2, unsigned short* __restrict__ w2t)
{
  __shared__ float lds[128*128];   // 64 KB, swizzled: (r,c) at [r*128 + (c^(r&31))]
  const int perMat = (DDIM/128)*(FDIM/128);   // 256
  int b = blockIdx.x;
  const float* w; unsigned short* wt; int R, C;
  if (b < NEXP*perMat) { w = w1; wt = w1t; R = DDIM; C = FDIM; }
  else { b -= NEXP*perMat; w = w2; wt = w2t; R = FDIM; C = DDIM; }
  int tpr = C >> 7;
  int e = b / perMat;
  int rem = b - e*perMat;
  int tr = rem / tpr;
  int tc = rem - tr*tpr;
  int tid = threadIdx.x;
  size_t ibase = (size_t)e*R*C + (size_t)(tr*128)*C + (size_t)(tc*128);
  size_t obase = (size_t)e*R*C + (size_t)(tc*128)*R + (size_t)(tr*128);
  // phase 1: non-temporal float4 loads, 512B contiguous per 32 lanes
#pragma unroll
  for (int i = 0; i < 8; i++) {
    int s = tid + i*512;
    int r = s >> 5;
    int c4 = (s & 31) << 2;
    f4v v = __builtin_nontemporal_load((const f4v*)(w + ibase + (size_t)r*C + c4));
    int xr = r & 31;
#pragma unroll
    for (int j = 0; j < 4; j++)
      lds[r*128 + ((c4 + j) ^ xr)] = v[j];
  }
  __syncthreads();
  // phase 2: out[oc][r8..r8+7] via u16x8 (16B) stores, 256B per out-row group
#pragma unroll
  for (int i = 0; i < 4; i++) {
    int s = tid + i*512;
    int oc = s >> 4;
    int r8 = (s & 15) << 3;
    u16x8 o;
#pragma unroll
    for (int j = 0; j < 8; j++) {
      int r = r8 + j;
      o[j] = f2bf(lds[r*128 + (oc ^ (r & 31))]);
    }
    *(u16x8*)(wt + obase + (size_t)oc*R + r8) = o;
  }
}

// ------ counting sort + compact tile list (single block) ------
__global__ __launch_bounds__(256) void permbuild_kernel(
    const int* __restrict__ topi, const int* __restrict__ counts,
    int* __restrict__ offsets, int* __restrict__ perm, int* __restrict__ islot,
    int* __restrict__ tlist, int* __restrict__ tcount)
{
  __shared__ int hist[256 * 8];
  __shared__ int offs[NEXP + 1];
  int tid = threadIdx.x;
  if (tid == 0) {
    int s = 0;
    for (int e = 0; e < 8; e++) { offs[e] = s; s += counts[e]; }
    offs[8] = s;
    for (int e = 0; e <= 8; e++) offsets[e] = offs[e];
    int k = 0;
    for (int e = 0; e < 8; e++) {
      int m = (counts[e] + 127) >> 7;
      for (int r = 0; r < m; r++) tlist[k++] = (e << 8) | r;
    }
    tcount[0] = k;
  }
  int cnt[8];
#pragma unroll
  for (int e = 0; e < 8; e++) cnt[e] = 0;
  int base = tid * 64;
  for (int i = 0; i < 64; i++) cnt[topi[base + i]]++;
#pragma unroll
  for (int e = 0; e < 8; e++) hist[tid*8 + e] = cnt[e];
  __syncthreads();
  if (tid < 8) {
    int s = 0;
    for (int th = 0; th < 256; th++) { int v = hist[th*8 + tid]; hist[th*8 + tid] = s; s += v; }
  }
  __syncthreads();
  int pos[8];
#pragma unroll
  for (int e = 0; e < 8; e++) pos[e] = offs[e] + hist[tid*8 + e];
  for (int i = 0; i < 64; i++) {
    int a = base + i;
    int e = topi[a];
    int p = pos[e]++;
    perm[p] = a >> 1;
    islot[a] = p;
  }
}

// ========= 128x128 grouped GEMM, m97-faithful + compact tile list ==========
// r10-verbatim loop, linear decode (id%8 = nt%8 pins each B-panel to one
// XCD's L2 -- measured optimal; r20's regroup thrashed B, +230MB FETCH).
// Cacheable H stores (r22: NT-H regressed +15us -- H benefits from L3).
// NO __launch_bounds__ (r12) / NO atomics (r18).

template<int KDIM, int NDIM, bool GELU>
__global__ void gemm128(
    const unsigned short* __restrict__ Asrc,
    const unsigned short* __restrict__ Bsrc,
    const float* __restrict__ bias,
    const int* __restrict__ perm,
    const int* __restrict__ offsets,
    const int* __restrict__ tlist,
    const int* __restrict__ tcount,
    void* __restrict__ Cout)
{
  constexpr int KT = KDIM / 64;
  constexpr int NT = NDIM / 128;
  int b = blockIdx.x;
  int ti = b / NT;
  int nt = b - ti * NT;
  if (ti >= tcount[0]) return;
  int code = tlist[ti];
  int e = code >> 8;
  int rt = code & 255;
  int off = offsets[e];
  int n_e = offsets[e+1] - off;

  __shared__ __align__(16) unsigned short lds[2 * 128 * 64];   // 32 KiB
  char* ldsA = (char*)lds;            // A: 128 rows x 128B
  char* ldsB = (char*)lds + 16384;    // B: 128 rows x 128B

  int tid = threadIdx.x;
  int lane = tid & 63;
  int wid = tid >> 6;          // 0..3
  int wr = wid >> 1;           // 0..1 (M strip)
  int wc = wid & 1;            // 0..1 (N strip)
  int tb0 = (lane >> 4) * 16;
  int rA = wr*64 + (lane & 15);
  int rB = wc*64 + (lane & 15);
  int xa  = (rA & 7) << 4;
  int xbw = (rB & 7) << 4;
  int aks0 = rA*128 + ( tb0       ^ xa);
  int aks1 = rA*128 + ((64 + tb0) ^ xa);
  int bks0 = rB*128 + ( tb0       ^ xbw);
  int bks1 = rB*128 + ((64 + tb0) ^ xbw);

  // staging: 4 A-slots + 4 B-slots per thread (1024 slots = 128 rows x 8 chunks)
  const char* srcA[4];
  const char* srcB[4];
#pragma unroll
  for (int i = 0; i < 4; i++) {
    int slot = tid + i*256;
    int r = slot >> 3;
    int kc = (slot & 7) ^ (r & 7);   // inverse swizzle on global k-chunk
    int g = off + rt*128 + r;
    if (g > NASG-1) g = NASG-1;
    size_t ar = GELU ? (size_t)perm[g] : (size_t)g;
    srcA[i] = (const char*)Asrc + (ar * KDIM + (size_t)kc*8) * 2;
    int col = nt*128 + r;
    srcB[i] = (const char*)Bsrc + (((size_t)e*NDIM + col) * KDIM + (size_t)kc*8) * 2;
  }
  int dstOff = tid * 16;

  f32x4 acc[4][4];
#pragma unroll
  for (int m = 0; m < 4; m++)
#pragma unroll
    for (int n = 0; n < 4; n++) acc[m][n] = (f32x4){0.f,0.f,0.f,0.f};

#pragma unroll 1
  for (int kt = 0; kt < KT; ++kt) {
    __syncthreads();   // previous compute done before overwrite
#pragma unroll
    for (int i = 0; i < 4; i++) {
      gload16(srcA[i] + (size_t)kt*128, ldsA + dstOff + i*4096);
      gload16(srcB[i] + (size_t)kt*128, ldsB + dstOff + i*4096);
    }
    __syncthreads();   // compiler-inserted vmcnt(0) drain: tile ready
#pragma unroll
    for (int ks = 0; ks < 2; ks++) {
      int ao = ks ? aks1 : aks0;
      int bo = ks ? bks1 : bks0;
      bf16x8 a[4], bb[4];
#pragma unroll
      for (int mi = 0; mi < 4; mi++) a[mi]  = *(const bf16x8*)(ldsA + mi*2048 + ao);
#pragma unroll
      for (int ni = 0; ni < 4; ni++) bb[ni] = *(const bf16x8*)(ldsB + ni*2048 + bo);
#pragma unroll
      for (int mi = 0; mi < 4; mi++)
#pragma unroll
        for (int ni = 0; ni < 4; ni++)
          acc[mi][ni] = __builtin_amdgcn_mfma_f32_16x16x32_bf16(a[mi], bb[ni], acc[mi][ni], 0, 0, 0);
    }
  }

  // epilogue
  int rq = (lane >> 4) * 4;
  int lc = lane & 15;
  if (GELU) {
    unsigned short* H = (unsigned short*)Cout;
#pragma unroll
    for (int mi = 0; mi < 4; mi++)
#pragma unroll
      for (int j = 0; j < 4; j++) {
        int sl = rt*128 + wr*64 + mi*16 + rq + j;
        if (sl < n_e) {
          size_t hrow = (size_t)(off + sl) * NDIM;
#pragma unroll
          for (int ni = 0; ni < 4; ni++) {
            int col = nt*128 + wc*64 + ni*16 + lc;
            float v = acc[mi][ni][j] + bias[e*NDIM + col];
            float g = 0.5f * v * (1.0f + erff(v * 0.70710678118654752f));
            H[hrow + col] = f2bf(g);
          }
        }
      }
  } else {
    unsigned short* Y = (unsigned short*)Cout;   // bf16 partial outputs
#pragma unroll
    for (int mi = 0; mi < 4; mi++)
#pragma unroll
      for (int j = 0; j < 4; j++) {
        int sl = rt*128 + wr*64 + mi*16 + rq + j;
        if (sl < n_e) {
          size_t yrow = (size_t)(off + sl) * NDIM;
#pragma unroll
          for (int ni = 0; ni < 4; ni++) {
            int col = nt*128 + wc*64 + ni*16 + lc;
            Y[yrow + col] = f2bf(acc[mi][ni][j]);
          }
        }
      }
  }
}

// ---------- combine: out[t] = sum_k w_k * (Y[slot_k] + b2[e_k]) ----------
__global__ __launch_bounds__(256) void combine_kernel(
    const unsigned short* __restrict__ Y, const float* __restrict__ b2,
    const int* __restrict__ topi, const float* __restrict__ topw,
    const int* __restrict__ islot, float* __restrict__ out)
{
  int t = blockIdx.x;
  int s0 = islot[t*2], s1 = islot[t*2+1];
  int e0 = topi[t*2],  e1 = topi[t*2+1];
  float w0 = topw[t*2], w1 = topw[t*2+1];
  int d = threadIdx.x * 4;
  u16x4 y0 = *(const u16x4*)(Y + (size_t)s0*DDIM + d);
  u16x4 y1 = *(const u16x4*)(Y + (size_t)s1*DDIM + d);
  f4v c0 = *(const f4v*)(b2 + (size_t)e0*DDIM + d);
  f4v c1 = *(const f4v*)(b2 + (size_t)e1*DDIM + d);
  f4v o;
#pragma unroll
  for (int j = 0; j < 4; j++)
    o[j] = w0*(bf2f(y0[j]) + c0[j]) + w1*(bf2f(y1[j]) + c1[j]);
  *(f4v*)(out + (size_t)t*DDIM + d) = o;
}

extern "C" void kernel_launch(void* const* d_in, const int* in_sizes, int n_in,
                              void* d_out, int out_size, void* d_ws, size_t ws_size,
                              hipStream_t stream) {
  const float* x  = (const float*)d_in[0];
  const float* w1 = (const float*)d_in[1];
  const float* b1 = (const float*)d_in[2];
  const float* w2 = (const float*)d_in[3];
  const float* b2 = (const float*)d_in[4];
  const float* rw = (const float*)d_in[5];
  const float* rb = (const float*)d_in[6];
  float* out = (float*)d_out;

  char* p = (char*)d_ws;
  size_t o = 0;
  auto take = [&](size_t bytes) -> void* {
    void* r = p + o;
    o = (o + bytes + 255) & ~(size_t)255;
    return r;
  };
  int*            counts  = (int*)take(NEXP * 4);
  int*            offsets = (int*)take((NEXP + 1) * 4);
  int*            tlist   = (int*)take(MAXTILES * 4);
  int*            tcount  = (int*)take(4);
  int*            topi    = (int*)take((size_t)NASG * 4);
  float*          topw    = (float*)take((size_t)NASG * 4);
  int*            perm    = (int*)take((size_t)NASG * 4);
  int*            islot   = (int*)take((size_t)NASG * 4);
  unsigned short* w1t     = (unsigned short*)take((size_t)NEXP * FDIM * DDIM * 2);
  unsigned short* xb      = (unsigned short*)take((size_t)TTOK * DDIM * 2);
  unsigned short* w2t     = (unsigned short*)take((size_t)NEXP * DDIM * FDIM * 2);
  unsigned short* H       = (unsigned short*)take((size_t)NASG * FDIM * 2);
  // Y (bf16, 32 MiB) aliases w1t (dead after gemm1, 64 MiB)
  unsigned short* Y       = w1t;

  if (o > ws_size) {   // workspace insufficient: fail visibly (zeros)
    hipMemsetAsync(d_out, 0, (size_t)out_size * 4, stream);
    return;
  }

  hipMemsetAsync(counts, 0, NEXP * 4, stream);

  router_kernel<<<TTOK/4, 256, 0, stream>>>(x, rw, rb, topi, topw, counts, xb);
  transpose2_kernel<<<2*NEXP*(DDIM/128)*(FDIM/128), 512, 0, stream>>>(w1, w1t, w2, w2t);
  permbuild_kernel<<<1, 256, 0, stream>>>(topi, counts, offsets, perm, islot, tlist, tcount);
  gemm128<DDIM, FDIM, true ><<<(MAXTILES-1)*(FDIM/128), 256, 0, stream>>>(xb, w1t, b1, perm, offsets, tlist, tcount, (void*)H);
  gemm128<FDIM, DDIM, false><<<(MAXTILES-1)*(DDIM/128), 256, 0, stream>>>(H, w2t, nullptr, perm, offsets, tlist, tcount, (void*)Y);
  combine_kernel<<<TTOK, 256, 0, stream>>>(Y, b2, topi, topw, islot, out);
}

// Round 24
// 705.670 us; speedup vs baseline: 1.0412x; 1.0185x over previous
//
#include <hip/hip_runtime.h>
#include <stdint.h>
#include <math.h>

#define TTOK 8192
#define DDIM 1024
#define FDIM 4096
#define NEXP 8
#define NASG (TTOK*2)
#define MAXTILES 136   // sum ceil(n_e/128) <= 128 + 7

typedef __attribute__((ext_vector_type(8))) short bf16x8;
typedef __attribute__((ext_vector_type(4))) float f32x4;
typedef __attribute__((ext_vector_type(4))) float f4v;
typedef __attribute__((ext_vector_type(4))) unsigned short u16x4;
typedef __attribute__((ext_vector_type(8))) unsigned short u16x8;

__device__ __forceinline__ unsigned short f2bf(float f) {
  union { float f; unsigned int u; } v; v.f = f;
  unsigned int u = v.u;
  u += 0x7fffu + ((u >> 16) & 1u);   // round-to-nearest-even
  return (unsigned short)(u >> 16);
}

__device__ __forceinline__ float bf2f(unsigned short s) {
  union { unsigned int u; float f; } v; v.u = (unsigned int)s << 16;
  return v.f;
}

__device__ __forceinline__ void gload16(const void* g, void* l) {
  __builtin_amdgcn_global_load_lds(
    (__attribute__((address_space(1))) unsigned int*)(uintptr_t)g,
    (__attribute__((address_space(3))) unsigned int*)(uintptr_t)l,
    16, 0, 0);
}

// ------ router: one wave per token, fp64 accumulate, vectorized loads ------
__global__ __launch_bounds__(256) void router_kernel(
    const float* __restrict__ x, const float* __restrict__ rw,
    const float* __restrict__ rb, int* __restrict__ topi,
    float* __restrict__ topw, int* __restrict__ counts,
    unsigned short* __restrict__ xb)
{
  int wave = threadIdx.x >> 6;
  int lane = threadIdx.x & 63;
  int t = blockIdx.x * 4 + wave;
  if (t >= TTOK) return;
  double acc[8];
#pragma unroll
  for (int e = 0; e < 8; e++) acc[e] = 0.0;
  const float* xr = x + (size_t)t * DDIM;
  unsigned short* xbr = xb + (size_t)t * DDIM;
#pragma unroll
  for (int i = 0; i < DDIM/256; i++) {
    int d4 = i*256 + lane*4;
    f4v xv4 = __builtin_nontemporal_load((const f4v*)(xr + d4));  // read-once
    u16x4 ov;
    ov[0] = f2bf(xv4[0]); ov[1] = f2bf(xv4[1]);
    ov[2] = f2bf(xv4[2]); ov[3] = f2bf(xv4[3]);
    *(u16x4*)(xbr + d4) = ov;
#pragma unroll
    for (int j = 0; j < 4; j++) {
      double xv = (double)xv4[j];
      const float* rwr = rw + (size_t)(d4 + j) * 8;
      f4v r0 = *(const f4v*)(rwr);
      f4v r1 = *(const f4v*)(rwr + 4);
      acc[0] += xv * (double)r0[0];
      acc[1] += xv * (double)r0[1];
      acc[2] += xv * (double)r0[2];
      acc[3] += xv * (double)r0[3];
      acc[4] += xv * (double)r1[0];
      acc[5] += xv * (double)r1[1];
      acc[6] += xv * (double)r1[2];
      acc[7] += xv * (double)r1[3];
    }
  }
#pragma unroll
  for (int e = 0; e < 8; e++) {
    for (int off = 32; off >= 1; off >>= 1)
      acc[e] += __shfl_xor(acc[e], off);
  }
  if (lane == 0) {
    float lg[8];
#pragma unroll
    for (int e = 0; e < 8; e++) lg[e] = (float)acc[e] + rb[e];
    int i0 = 0;
    for (int e = 1; e < 8; e++) if (lg[e] > lg[i0]) i0 = e;   // ties -> lowest idx
    int i1 = -1;
    for (int e = 0; e < 8; e++) {
      if (e == i0) continue;
      if (i1 < 0 || lg[e] > lg[i1]) i1 = e;
    }
    double z = exp((double)lg[i1] - (double)lg[i0]);
    float w0 = (float)(1.0 / (1.0 + z));
    topi[t*2]   = i0;  topi[t*2+1] = i1;
    topw[t*2]   = w0;  topw[t*2+1] = 1.0f - w0;
    atomicAdd(&counts[i0], 1);
    atomicAdd(&counts[i1], 1);
  }
}

// ---- w1 transpose+convert, 128x128 tiles, XOR-swizzled 64KB LDS ----
// [E][DDIM][FDIM] f32 -> [E][FDIM][DDIM] bf16. NT f32 reads keep bf16 output
// L3-resident for gemm1 (measured -27us/gemm). Launch with 2048 blocks.
__global__ __launch_bounds__(512) void transpose2_kernel(
    const float* __restrict__ w1, unsigned short* __restrict__ w1t,
    const float* __restrict__ w2, unsigned short* __restrict__ w2t)
{
  __shared__ float lds[128*128];   // 64 KB, swizzled: (r,c) at [r*128 + (c^(r&31))]
  const int perMat = (DDIM/128)*(FDIM/128);   // 256
  int b = blockIdx.x;
  const float* w; unsigned short* wt; int R, C;
  if (b < NEXP*perMat) { w = w1; wt = w1t; R = DDIM; C = FDIM; }
  else { b -= NEXP*perMat; w = w2; wt = w2t; R = FDIM; C = DDIM; }
  int tpr = C >> 7;
  int e = b / perMat;
  int rem = b - e*perMat;
  int tr = rem / tpr;
  int tc = rem - tr*tpr;
  int tid = threadIdx.x;
  size_t ibase = (size_t)e*R*C + (size_t)(tr*128)*C + (size_t)(tc*128);
  size_t obase = (size_t)e*R*C + (size_t)(tc*128)*R + (size_t)(tr*128);
  // phase 1: non-temporal float4 loads, 512B contiguous per 32 lanes
#pragma unroll
  for (int i = 0; i < 8; i++) {
    int s = tid + i*512;
    int r = s >> 5;
    int c4 = (s & 31) << 2;
    f4v v = __builtin_nontemporal_load((const f4v*)(w + ibase + (size_t)r*C + c4));
    int xr = r & 31;
#pragma unroll
    for (int j = 0; j < 4; j++)
      lds[r*128 + ((c4 + j) ^ xr)] = v[j];
  }
  __syncthreads();
  // phase 2: out[oc][r8..r8+7] via u16x8 (16B) stores, 256B per out-row group
#pragma unroll
  for (int i = 0; i < 4; i++) {
    int s = tid + i*512;
    int oc = s >> 4;
    int r8 = (s & 15) << 3;
    u16x8 o;
#pragma unroll
    for (int j = 0; j < 8; j++) {
      int r = r8 + j;
      o[j] = f2bf(lds[r*128 + (oc ^ (r & 31))]);
    }
    *(u16x8*)(wt + obase + (size_t)oc*R + r8) = o;
  }
}

// ------ counting sort + compact tile list (single block) ------
__global__ __launch_bounds__(256) void permbuild_kernel(
    const int* __restrict__ topi, const int* __restrict__ counts,
    int* __restrict__ offsets, int* __restrict__ perm, int* __restrict__ islot,
    int* __restrict__ tlist, int* __restrict__ tcount)
{
  __shared__ int hist[256 * 8];
  __shared__ int offs[NEXP + 1];
  int tid = threadIdx.x;
  if (tid == 0) {
    int s = 0;
    for (int e = 0; e < 8; e++) { offs[e] = s; s += counts[e]; }
    offs[8] = s;
    for (int e = 0; e <= 8; e++) offsets[e] = offs[e];
    int k = 0;
    for (int e = 0; e < 8; e++) {
      int m = (counts[e] + 127) >> 7;
      for (int r = 0; r < m; r++) tlist[k++] = (e << 8) | r;
    }
    tcount[0] = k;
  }
  int cnt[8];
#pragma unroll
  for (int e = 0; e < 8; e++) cnt[e] = 0;
  int base = tid * 64;
  for (int i = 0; i < 64; i++) cnt[topi[base + i]]++;
#pragma unroll
  for (int e = 0; e < 8; e++) hist[tid*8 + e] = cnt[e];
  __syncthreads();
  if (tid < 8) {
    int s = 0;
    for (int th = 0; th < 256; th++) { int v = hist[th*8 + tid]; hist[th*8 + tid] = s; s += v; }
  }
  __syncthreads();
  int pos[8];
#pragma unroll
  for (int e = 0; e < 8; e++) pos[e] = offs[e] + hist[tid*8 + e];
  for (int i = 0; i < 64; i++) {
    int a = base + i;
    int e = topi[a];
    int p = pos[e]++;
    perm[p] = a >> 1;
    islot[a] = p;
  }
}

// ========= 128x128 grouped GEMM, m97-faithful + compact tile list ==========
// r10-verbatim loop, linear decode (id%8 = nt%8 pins each B-panel to one
// XCD's L2 -- measured optimal). Cacheable H/Y stores (r22: NT-H regressed).
// NO __launch_bounds__ (r12) / NO atomics (r18).
// FUSET2: blocks past the gemm range perform the w2 transpose (64x64 tiles,
// r15-proven path) -- w2t has no consumer until gemm2, so this hides its
// BW-bound work under gemm1's latency-bound execution. LDS unioned in smem.

template<int KDIM, int NDIM, bool GELU, bool FUSET2>
__global__ void gemm128(
    const unsigned short* __restrict__ Asrc,
    const unsigned short* __restrict__ Bsrc,
    const float* __restrict__ bias,
    const int* __restrict__ perm,
    const int* __restrict__ offsets,
    const int* __restrict__ tlist,
    const int* __restrict__ tcount,
    const float* __restrict__ w2src,
    unsigned short* __restrict__ w2dst,
    void* __restrict__ Cout)
{
  constexpr int KT = KDIM / 64;
  constexpr int NT = NDIM / 128;
  constexpr int G1B = (MAXTILES-1) * NT;

  __shared__ __align__(16) char smem[32768];   // union: gemm 32KB | transpose 16.6KB

  if constexpr (FUSET2) {
    if (blockIdx.x >= G1B) {
      // ---- w2 transpose tile (r15-proven 64x64 path): [E][FDIM][DDIM] f32
      // -> [E][DDIM][FDIM] bf16. NT loads protect L3 residency of gemm operands.
      float (*tile)[65] = (float(*)[65])smem;
      int b = blockIdx.x - G1B;
      const int R = FDIM, C = DDIM;
      const int tilesPerRow = C >> 6;              // 16
      const int tilesPerMat = (R >> 6) * tilesPerRow;  // 1024
      int e = b / tilesPerMat;
      int rem = b - e * tilesPerMat;
      int tr = rem / tilesPerRow;
      int tc = rem - tr * tilesPerRow;
      int tid = threadIdx.x;
      size_t ibase = (size_t)e*R*C + ((size_t)tr*64)*C + (size_t)tc*64;
#pragma unroll
      for (int i = 0; i < 4; i++) {
        int idx = tid + i*256;          // 0..1023
        int r  = idx >> 4;              // input row 0..63
        int c4 = (idx & 15) * 4;        // input col group
        f4v v = __builtin_nontemporal_load((const f4v*)(w2src + ibase + (size_t)r*C + c4));
        tile[r][c4+0] = v[0];
        tile[r][c4+1] = v[1];
        tile[r][c4+2] = v[2];
        tile[r][c4+3] = v[3];
      }
      __syncthreads();
      size_t obase = (size_t)e*R*C + ((size_t)tc*64)*R + (size_t)tr*64;
#pragma unroll
      for (int i = 0; i < 4; i++) {
        int idx = tid + i*256;
        int r  = idx >> 4;              // output row 0..63
        int c4 = (idx & 15) * 4;        // output col group
        u16x4 v;
        v[0] = f2bf(tile[c4+0][r]);
        v[1] = f2bf(tile[c4+1][r]);
        v[2] = f2bf(tile[c4+2][r]);
        v[3] = f2bf(tile[c4+3][r]);
        *(u16x4*)(w2dst + obase + (size_t)r*R + c4) = v;
      }
      return;
    }
  }

  int b = blockIdx.x;
  int ti = b / NT;
  int nt = b - ti * NT;
  if (ti >= tcount[0]) return;
  int code = tlist[ti];
  int e = code >> 8;
  int rt = code & 255;
  int off = offsets[e];
  int n_e = offsets[e+1] - off;

  char* ldsA = smem;            // A: 128 rows x 128B
  char* ldsB = smem + 16384;    // B: 128 rows x 128B

  int tid = threadIdx.x;
  int lane = tid & 63;
  int wid = tid >> 6;          // 0..3
  int wr = wid >> 1;           // 0..1 (M strip)
  int wc = wid & 1;            // 0..1 (N strip)
  int tb0 = (lane >> 4) * 16;
  int rA = wr*64 + (lane & 15);
  int rB = wc*64 + (lane & 15);
  int xa  = (rA & 7) << 4;
  int xbw = (rB & 7) << 4;
  int aks0 = rA*128 + ( tb0       ^ xa);
  int aks1 = rA*128 + ((64 + tb0) ^ xa);
  int bks0 = rB*128 + ( tb0       ^ xbw);
  int bks1 = rB*128 + ((64 + tb0) ^ xbw);

  // staging: 4 A-slots + 4 B-slots per thread (1024 slots = 128 rows x 8 chunks)
  const char* srcA[4];
  const char* srcB[4];
#pragma unroll
  for (int i = 0; i < 4; i++) {
    int slot = tid + i*256;
    int r = slot >> 3;
    int kc = (slot & 7) ^ (r & 7);   // inverse swizzle on global k-chunk
    int g = off + rt*128 + r;
    if (g > NASG-1) g = NASG-1;
    size_t ar = GELU ? (size_t)perm[g] : (size_t)g;
    srcA[i] = (const char*)Asrc + (ar * KDIM + (size_t)kc*8) * 2;
    int col = nt*128 + r;
    srcB[i] = (const char*)Bsrc + (((size_t)e*NDIM + col) * KDIM + (size_t)kc*8) * 2;
  }
  int dstOff = tid * 16;

  f32x4 acc[4][4];
#pragma unroll
  for (int m = 0; m < 4; m++)
#pragma unroll
    for (int n = 0; n < 4; n++) acc[m][n] = (f32x4){0.f,0.f,0.f,0.f};

#pragma unroll 1
  for (int kt = 0; kt < KT; ++kt) {
    __syncthreads();   // previous compute done before overwrite
#pragma unroll
    for (int i = 0; i < 4; i++) {
      gload16(srcA[i] + (size_t)kt*128, ldsA + dstOff + i*4096);
      gload16(srcB[i] + (size_t)kt*128, ldsB + dstOff + i*4096);
    }
    __syncthreads();   // compiler-inserted vmcnt(0) drain: tile ready
#pragma unroll
    for (int ks = 0; ks < 2; ks++) {
      int ao = ks ? aks1 : aks0;
      int bo = ks ? bks1 : bks0;
      bf16x8 a[4], bb[4];
#pragma unroll
      for (int mi = 0; mi < 4; mi++) a[mi]  = *(const bf16x8*)(ldsA + mi*2048 + ao);
#pragma unroll
      for (int ni = 0; ni < 4; ni++) bb[ni] = *(const bf16x8*)(ldsB + ni*2048 + bo);
#pragma unroll
      for (int mi = 0; mi < 4; mi++)
#pragma unroll
        for (int ni = 0; ni < 4; ni++)
          acc[mi][ni] = __builtin_amdgcn_mfma_f32_16x16x32_bf16(a[mi], bb[ni], acc[mi][ni], 0, 0, 0);
    }
  }

  // epilogue
  int rq = (lane >> 4) * 4;
  int lc = lane & 15;
  if (GELU) {
    unsigned short* H = (unsigned short*)Cout;
#pragma unroll
    for (int mi = 0; mi < 4; mi++)
#pragma unroll
      for (int j = 0; j < 4; j++) {
        int sl = rt*128 + wr*64 + mi*16 + rq + j;
        if (sl < n_e) {
          size_t hrow = (size_t)(off + sl) * NDIM;
#pragma unroll
          for (int ni = 0; ni < 4; ni++) {
            int col = nt*128 + wc*64 + ni*16 + lc;
            float v = acc[mi][ni][j] + bias[e*NDIM + col];
            float g = 0.5f * v * (1.0f + erff(v * 0.70710678118654752f));
            H[hrow + col] = f2bf(g);
          }
        }
      }
  } else {
    unsigned short* Y = (unsigned short*)Cout;   // bf16 partial outputs
#pragma unroll
    for (int mi = 0; mi < 4; mi++)
#pragma unroll
      for (int j = 0; j < 4; j++) {
        int sl = rt*128 + wr*64 + mi*16 + rq + j;
        if (sl < n_e) {
          size_t yrow = (size_t)(off + sl) * NDIM;
#pragma unroll
          for (int ni = 0; ni < 4; ni++) {
            int col = nt*128 + wc*64 + ni*16 + lc;
            Y[yrow + col] = f2bf(acc[mi][ni][j]);
          }
        }
      }
  }
}

// ---------- combine: out[t] = sum_k w_k * (Y[slot_k] + b2[e_k]) ----------
__global__ __launch_bounds__(256) void combine_kernel(
    const unsigned short* __restrict__ Y, const float* __restrict__ b2,
    const int* __restrict__ topi, const float* __restrict__ topw,
    const int* __restrict__ islot, float* __restrict__ out)
{
  int t = blockIdx.x;
  int s0 = islot[t*2], s1 = islot[t*2+1];
  int e0 = topi[t*2],  e1 = topi[t*2+1];
  float w0 = topw[t*2], w1 = topw[t*2+1];
  int d = threadIdx.x * 4;
  u16x4 y0 = *(const u16x4*)(Y + (size_t)s0*DDIM + d);
  u16x4 y1 = *(const u16x4*)(Y + (size_t)s1*DDIM + d);
  f4v c0 = *(const f4v*)(b2 + (size_t)e0*DDIM + d);
  f4v c1 = *(const f4v*)(b2 + (size_t)e1*DDIM + d);
  f4v o;
#pragma unroll
  for (int j = 0; j < 4; j++)
    o[j] = w0*(bf2f(y0[j]) + c0[j]) + w1*(bf2f(y1[j]) + c1[j]);
  *(f4v*)(out + (size_t)t*DDIM + d) = o;
}

extern "C" void kernel_launch(void* const* d_in, const int* in_sizes, int n_in,
                              void* d_out, int out_size, void* d_ws, size_t ws_size,
                              hipStream_t stream) {
  const float* x  = (const float*)d_in[0];
  const float* w1 = (const float*)d_in[1];
  const float* b1 = (const float*)d_in[2];
  const float* w2 = (const float*)d_in[3];
  const float* b2 = (const float*)d_in[4];
  const float* rw = (const float*)d_in[5];
  const float* rb = (const float*)d_in[6];
  float* out = (float*)d_out;

  char* p = (char*)d_ws;
  size_t o = 0;
  auto take = [&](size_t bytes) -> void* {
    void* r = p + o;
    o = (o + bytes + 255) & ~(size_t)255;
    return r;
  };
  int*            counts  = (int*)take(NEXP * 4);
  int*            offsets = (int*)take((NEXP + 1) * 4);
  int*            tlist   = (int*)take(MAXTILES * 4);
  int*            tcount  = (int*)take(4);
  int*            topi    = (int*)take((size_t)NASG * 4);
  float*          topw    = (float*)take((size_t)NASG * 4);
  int*            perm    = (int*)take((size_t)NASG * 4);
  int*            islot   = (int*)take((size_t)NASG * 4);
  unsigned short* w1t     = (unsigned short*)take((size_t)NEXP * FDIM * DDIM * 2);
  unsigned short* xb      = (unsigned short*)take((size_t)TTOK * DDIM * 2);
  unsigned short* w2t     = (unsigned short*)take((size_t)NEXP * DDIM * FDIM * 2);
  unsigned short* H       = (unsigned short*)take((size_t)NASG * FDIM * 2);
  // Y (bf16, 32 MiB) aliases w1t (dead after gemm1, 64 MiB)
  unsigned short* Y       = w1t;

  if (o > ws_size) {   // workspace insufficient: fail visibly (zeros)
    hipMemsetAsync(d_out, 0, (size_t)out_size * 4, stream);
    return;
  }

  hipMemsetAsync(counts, 0, NEXP * 4, stream);

  const int G1B = (MAXTILES-1)*(FDIM/128);          // 4320 gemm blocks
  const int T2B = NEXP*(FDIM/64)*(DDIM/64);         // 8192 w2 transpose tiles

  router_kernel<<<TTOK/4, 256, 0, stream>>>(x, rw, rb, topi, topw, counts, xb);
  transpose2_kernel<<<NEXP*(DDIM/128)*(FDIM/128), 512, 0, stream>>>(w1, w1t, w2, w2t);  // w1 only
  permbuild_kernel<<<1, 256, 0, stream>>>(topi, counts, offsets, perm, islot, tlist, tcount);
  gemm128<DDIM, FDIM, true , true ><<<G1B + T2B, 256, 0, stream>>>(
      xb, w1t, b1, perm, offsets, tlist, tcount, w2, w2t, (void*)H);
  gemm128<FDIM, DDIM, false, false><<<(MAXTILES-1)*(DDIM/128), 256, 0, stream>>>(
      H, w2t, nullptr, perm, offsets, tlist, tcount, nullptr, nullptr, (void*)Y);
  combine_kernel<<<TTOK, 256, 0, stream>>>(Y, b2, topi, topw, islot, out);
}

// Round 25
// 687.737 us; speedup vs baseline: 1.0684x; 1.0261x over previous
//
#include <hip/hip_runtime.h>
#include <stdint.h>
#include <math.h>

#define TTOK 8192
#define DDIM 1024
#define FDIM 4096
#define NEXP 8
#define NASG (TTOK*2)
#define MAXTILES 136   // sum ceil(n_e/128) <= 128 + 7
#define PRB (TTOK/8)   // 1024 router blocks @ 512 threads (8 tokens/block)

typedef __attribute__((ext_vector_type(8))) short bf16x8;
typedef __attribute__((ext_vector_type(4))) float f32x4;
typedef __attribute__((ext_vector_type(4))) float f4v;
typedef __attribute__((ext_vector_type(4))) unsigned short u16x4;
typedef __attribute__((ext_vector_type(8))) unsigned short u16x8;

__device__ __forceinline__ unsigned short f2bf(float f) {
  union { float f; unsigned int u; } v; v.f = f;
  unsigned int u = v.u;
  u += 0x7fffu + ((u >> 16) & 1u);   // round-to-nearest-even
  return (unsigned short)(u >> 16);
}

__device__ __forceinline__ float bf2f(unsigned short s) {
  union { unsigned int u; float f; } v; v.u = (unsigned int)s << 16;
  return v.f;
}

__device__ __forceinline__ void gload16(const void* g, void* l) {
  __builtin_amdgcn_global_load_lds(
    (__attribute__((address_space(1))) unsigned int*)(uintptr_t)g,
    (__attribute__((address_space(3))) unsigned int*)(uintptr_t)l,
    16, 0, 0);
}

// ===== prep: router (blocks 0..PRB) + w1 transpose (rest), co-scheduled =====
// router: one wave per token, fp64 accumulate, vectorized NT loads, emits xb.
// w1 transpose: 128x128 tiles, XOR-swizzled 64KB LDS, NT f32 reads (keeps the
// bf16 output L3-resident for gemm1), u16x8 stores. r24's branch-union pattern.
__global__ __launch_bounds__(512) void prep_kernel(
    const float* __restrict__ x, const float* __restrict__ rw,
    const float* __restrict__ rb, int* __restrict__ topi,
    float* __restrict__ topw, int* __restrict__ counts,
    unsigned short* __restrict__ xb,
    const float* __restrict__ w1, unsigned short* __restrict__ w1t)
{
  __shared__ float lds[128*128];   // 64 KB (transpose branch only)
  int blk = blockIdx.x;
  if (blk < PRB) {
    // ---------------- router ----------------
    int wave = threadIdx.x >> 6;
    int lane = threadIdx.x & 63;
    int t = blk * 8 + wave;
    if (t >= TTOK) return;
    double acc[8];
#pragma unroll
    for (int e = 0; e < 8; e++) acc[e] = 0.0;
    const float* xr = x + (size_t)t * DDIM;
    unsigned short* xbr = xb + (size_t)t * DDIM;
#pragma unroll
    for (int i = 0; i < DDIM/256; i++) {
      int d4 = i*256 + lane*4;
      f4v xv4 = __builtin_nontemporal_load((const f4v*)(xr + d4));  // read-once
      u16x4 ov;
      ov[0] = f2bf(xv4[0]); ov[1] = f2bf(xv4[1]);
      ov[2] = f2bf(xv4[2]); ov[3] = f2bf(xv4[3]);
      *(u16x4*)(xbr + d4) = ov;
#pragma unroll
      for (int j = 0; j < 4; j++) {
        double xv = (double)xv4[j];
        const float* rwr = rw + (size_t)(d4 + j) * 8;
        f4v r0 = *(const f4v*)(rwr);
        f4v r1 = *(const f4v*)(rwr + 4);
        acc[0] += xv * (double)r0[0];
        acc[1] += xv * (double)r0[1];
        acc[2] += xv * (double)r0[2];
        acc[3] += xv * (double)r0[3];
        acc[4] += xv * (double)r1[0];
        acc[5] += xv * (double)r1[1];
        acc[6] += xv * (double)r1[2];
        acc[7] += xv * (double)r1[3];
      }
    }
#pragma unroll
    for (int e = 0; e < 8; e++) {
      for (int off = 32; off >= 1; off >>= 1)
        acc[e] += __shfl_xor(acc[e], off);
    }
    if (lane == 0) {
      float lg[8];
#pragma unroll
      for (int e = 0; e < 8; e++) lg[e] = (float)acc[e] + rb[e];
      int i0 = 0;
      for (int e = 1; e < 8; e++) if (lg[e] > lg[i0]) i0 = e;   // ties -> lowest idx
      int i1 = -1;
      for (int e = 0; e < 8; e++) {
        if (e == i0) continue;
        if (i1 < 0 || lg[e] > lg[i1]) i1 = e;
      }
      double z = exp((double)lg[i1] - (double)lg[i0]);
      float w0 = (float)(1.0 / (1.0 + z));
      topi[t*2]   = i0;  topi[t*2+1] = i1;
      topw[t*2]   = w0;  topw[t*2+1] = 1.0f - w0;
      atomicAdd(&counts[i0], 1);
      atomicAdd(&counts[i1], 1);
    }
    return;
  }
  // ---------------- w1 transpose: [E][DDIM][FDIM] f32 -> [E][FDIM][DDIM] bf16
  int b = blk - PRB;
  const int R = DDIM, C = FDIM;
  const int perMat = (DDIM/128)*(FDIM/128);   // 256
  int tpr = C >> 7;
  int e = b / perMat;
  int rem = b - e*perMat;
  int tr = rem / tpr;
  int tc = rem - tr*tpr;
  int tid = threadIdx.x;
  size_t ibase = (size_t)e*R*C + (size_t)(tr*128)*C + (size_t)(tc*128);
  size_t obase = (size_t)e*R*C + (size_t)(tc*128)*R + (size_t)(tr*128);
  // phase 1: non-temporal float4 loads, 512B contiguous per 32 lanes
#pragma unroll
  for (int i = 0; i < 8; i++) {
    int s = tid + i*512;
    int r = s >> 5;
    int c4 = (s & 31) << 2;
    f4v v = __builtin_nontemporal_load((const f4v*)(w1 + ibase + (size_t)r*C + c4));
    int xr = r & 31;
#pragma unroll
    for (int j = 0; j < 4; j++)
      lds[r*128 + ((c4 + j) ^ xr)] = v[j];
  }
  __syncthreads();
  // phase 2: out[oc][r8..r8+7] via u16x8 (16B) stores, 256B per out-row group
#pragma unroll
  for (int i = 0; i < 4; i++) {
    int s = tid + i*512;
    int oc = s >> 4;
    int r8 = (s & 15) << 3;
    u16x8 o;
#pragma unroll
    for (int j = 0; j < 8; j++) {
      int r = r8 + j;
      o[j] = f2bf(lds[r*128 + (oc ^ (r & 31))]);
    }
    *(u16x8*)(w1t + obase + (size_t)oc*R + r8) = o;
  }
}

// ------ counting sort + compact tile list (single block) ------
__global__ __launch_bounds__(256) void permbuild_kernel(
    const int* __restrict__ topi, const int* __restrict__ counts,
    int* __restrict__ offsets, int* __restrict__ perm, int* __restrict__ islot,
    int* __restrict__ tlist, int* __restrict__ tcount)
{
  __shared__ int hist[256 * 8];
  __shared__ int offs[NEXP + 1];
  int tid = threadIdx.x;
  if (tid == 0) {
    int s = 0;
    for (int e = 0; e < 8; e++) { offs[e] = s; s += counts[e]; }
    offs[8] = s;
    for (int e = 0; e <= 8; e++) offsets[e] = offs[e];
    int k = 0;
    for (int e = 0; e < 8; e++) {
      int m = (counts[e] + 127) >> 7;
      for (int r = 0; r < m; r++) tlist[k++] = (e << 8) | r;
    }
    tcount[0] = k;
  }
  int cnt[8];
#pragma unroll
  for (int e = 0; e < 8; e++) cnt[e] = 0;
  int base = tid * 64;
  for (int i = 0; i < 64; i++) cnt[topi[base + i]]++;
#pragma unroll
  for (int e = 0; e < 8; e++) hist[tid*8 + e] = cnt[e];
  __syncthreads();
  if (tid < 8) {
    int s = 0;
    for (int th = 0; th < 256; th++) { int v = hist[th*8 + tid]; hist[th*8 + tid] = s; s += v; }
  }
  __syncthreads();
  int pos[8];
#pragma unroll
  for (int e = 0; e < 8; e++) pos[e] = offs[e] + hist[tid*8 + e];
  for (int i = 0; i < 64; i++) {
    int a = base + i;
    int e = topi[a];
    int p = pos[e]++;
    perm[p] = a >> 1;
    islot[a] = p;
  }
}

// ========= 128x128 grouped GEMM, m97-faithful + compact tile list ==========
// r10-verbatim loop, linear decode (id%8 = nt%8 pins each B-panel to one
// XCD's L2 -- measured optimal). Cacheable H/Y stores (r22: NT-H regressed).
// NO __launch_bounds__ (r12) / NO atomics (r18).
// FUSET2: blocks past the gemm range perform the w2 transpose (64x64 tiles,
// r15-proven path) -- w2t has no consumer until gemm2, so this hides its
// BW-bound work under gemm1's latency-bound execution. LDS unioned in smem.

template<int KDIM, int NDIM, bool GELU, bool FUSET2>
__global__ void gemm128(
    const unsigned short* __restrict__ Asrc,
    const unsigned short* __restrict__ Bsrc,
    const float* __restrict__ bias,
    const int* __restrict__ perm,
    const int* __restrict__ offsets,
    const int* __restrict__ tlist,
    const int* __restrict__ tcount,
    const float* __restrict__ w2src,
    unsigned short* __restrict__ w2dst,
    void* __restrict__ Cout)
{
  constexpr int KT = KDIM / 64;
  constexpr int NT = NDIM / 128;
  constexpr int G1B = (MAXTILES-1) * NT;

  __shared__ __align__(16) char smem[32768];   // union: gemm 32KB | transpose 16.6KB

  if constexpr (FUSET2) {
    if (blockIdx.x >= G1B) {
      // ---- w2 transpose tile (64x64 path): [E][FDIM][DDIM] f32
      // -> [E][DDIM][FDIM] bf16. NT loads protect L3 residency of gemm operands.
      float (*tile)[65] = (float(*)[65])smem;
      int b = blockIdx.x - G1B;
      const int R = FDIM, C = DDIM;
      const int tilesPerRow = C >> 6;              // 16
      const int tilesPerMat = (R >> 6) * tilesPerRow;  // 1024
      int e = b / tilesPerMat;
      int rem = b - e * tilesPerMat;
      int tr = rem / tilesPerRow;
      int tc = rem - tr * tilesPerRow;
      int tid = threadIdx.x;
      size_t ibase = (size_t)e*R*C + ((size_t)tr*64)*C + (size_t)tc*64;
#pragma unroll
      for (int i = 0; i < 4; i++) {
        int idx = tid + i*256;          // 0..1023
        int r  = idx >> 4;              // input row 0..63
        int c4 = (idx & 15) * 4;        // input col group
        f4v v = __builtin_nontemporal_load((const f4v*)(w2src + ibase + (size_t)r*C + c4));
        tile[r][c4+0] = v[0];
        tile[r][c4+1] = v[1];
        tile[r][c4+2] = v[2];
        tile[r][c4+3] = v[3];
      }
      __syncthreads();
      size_t obase = (size_t)e*R*C + ((size_t)tc*64)*R + (size_t)tr*64;
#pragma unroll
      for (int i = 0; i < 4; i++) {
        int idx = tid + i*256;
        int r  = idx >> 4;              // output row 0..63
        int c4 = (idx & 15) * 4;        // output col group
        u16x4 v;
        v[0] = f2bf(tile[c4+0][r]);
        v[1] = f2bf(tile[c4+1][r]);
        v[2] = f2bf(tile[c4+2][r]);
        v[3] = f2bf(tile[c4+3][r]);
        *(u16x4*)(w2dst + obase + (size_t)r*R + c4) = v;
      }
      return;
    }
  }

  int b = blockIdx.x;
  int ti = b / NT;
  int nt = b - ti * NT;
  if (ti >= tcount[0]) return;
  int code = tlist[ti];
  int e = code >> 8;
  int rt = code & 255;
  int off = offsets[e];
  int n_e = offsets[e+1] - off;

  char* ldsA = smem;            // A: 128 rows x 128B
  char* ldsB = smem + 16384;    // B: 128 rows x 128B

  int tid = threadIdx.x;
  int lane = tid & 63;
  int wid = tid >> 6;          // 0..3
  int wr = wid >> 1;           // 0..1 (M strip)
  int wc = wid & 1;            // 0..1 (N strip)
  int tb0 = (lane >> 4) * 16;
  int rA = wr*64 + (lane & 15);
  int rB = wc*64 + (lane & 15);
  int xa  = (rA & 7) << 4;
  int xbw = (rB & 7) << 4;
  int aks0 = rA*128 + ( tb0       ^ xa);
  int aks1 = rA*128 + ((64 + tb0) ^ xa);
  int bks0 = rB*128 + ( tb0       ^ xbw);
  int bks1 = rB*128 + ((64 + tb0) ^ xbw);

  // staging: 4 A-slots + 4 B-slots per thread (1024 slots = 128 rows x 8 chunks)
  const char* srcA[4];
  const char* srcB[4];
#pragma unroll
  for (int i = 0; i < 4; i++) {
    int slot = tid + i*256;
    int r = slot >> 3;
    int kc = (slot & 7) ^ (r & 7);   // inverse swizzle on global k-chunk
    int g = off + rt*128 + r;
    if (g > NASG-1) g = NASG-1;
    size_t ar = GELU ? (size_t)perm[g] : (size_t)g;
    srcA[i] = (const char*)Asrc + (ar * KDIM + (size_t)kc*8) * 2;
    int col = nt*128 + r;
    srcB[i] = (const char*)Bsrc + (((size_t)e*NDIM + col) * KDIM + (size_t)kc*8) * 2;
  }
  int dstOff = tid * 16;

  f32x4 acc[4][4];
#pragma unroll
  for (int m = 0; m < 4; m++)
#pragma unroll
    for (int n = 0; n < 4; n++) acc[m][n] = (f32x4){0.f,0.f,0.f,0.f};

#pragma unroll 1
  for (int kt = 0; kt < KT; ++kt) {
    __syncthreads();   // previous compute done before overwrite
#pragma unroll
    for (int i = 0; i < 4; i++) {
      gload16(srcA[i] + (size_t)kt*128, ldsA + dstOff + i*4096);
      gload16(srcB[i] + (size_t)kt*128, ldsB + dstOff + i*4096);
    }
    __syncthreads();   // compiler-inserted vmcnt(0) drain: tile ready
#pragma unroll
    for (int ks = 0; ks < 2; ks++) {
      int ao = ks ? aks1 : aks0;
      int bo = ks ? bks1 : bks0;
      bf16x8 a[4], bb[4];
#pragma unroll
      for (int mi = 0; mi < 4; mi++) a[mi]  = *(const bf16x8*)(ldsA + mi*2048 + ao);
#pragma unroll
      for (int ni = 0; ni < 4; ni++) bb[ni] = *(const bf16x8*)(ldsB + ni*2048 + bo);
#pragma unroll
      for (int mi = 0; mi < 4; mi++)
#pragma unroll
        for (int ni = 0; ni < 4; ni++)
          acc[mi][ni] = __builtin_amdgcn_mfma_f32_16x16x32_bf16(a[mi], bb[ni], acc[mi][ni], 0, 0, 0);
    }
  }

  // epilogue
  int rq = (lane >> 4) * 4;
  int lc = lane & 15;
  if (GELU) {
    unsigned short* H = (unsigned short*)Cout;
#pragma unroll
    for (int mi = 0; mi < 4; mi++)
#pragma unroll
      for (int j = 0; j < 4; j++) {
        int sl = rt*128 + wr*64 + mi*16 + rq + j;
        if (sl < n_e) {
          size_t hrow = (size_t)(off + sl) * NDIM;
#pragma unroll
          for (int ni = 0; ni < 4; ni++) {
            int col = nt*128 + wc*64 + ni*16 + lc;
            float v = acc[mi][ni][j] + bias[e*NDIM + col];
            float g = 0.5f * v * (1.0f + erff(v * 0.70710678118654752f));
            H[hrow + col] = f2bf(g);
          }
        }
      }
  } else {
    unsigned short* Y = (unsigned short*)Cout;   // bf16 partial outputs
#pragma unroll
    for (int mi = 0; mi < 4; mi++)
#pragma unroll
      for (int j = 0; j < 4; j++) {
        int sl = rt*128 + wr*64 + mi*16 + rq + j;
        if (sl < n_e) {
          size_t yrow = (size_t)(off + sl) * NDIM;
#pragma unroll
          for (int ni = 0; ni < 4; ni++) {
            int col = nt*128 + wc*64 + ni*16 + lc;
            Y[yrow + col] = f2bf(acc[mi][ni][j]);
          }
        }
      }
  }
}

// ---------- combine: out[t] = sum_k w_k * (Y[slot_k] + b2[e_k]) ----------
__global__ __launch_bounds__(256) void combine_kernel(
    const unsigned short* __restrict__ Y, const float* __restrict__ b2,
    const int* __restrict__ topi, const float* __restrict__ topw,
    const int* __restrict__ islot, float* __restrict__ out)
{
  int t = blockIdx.x;
  int s0 = islot[t*2], s1 = islot[t*2+1];
  int e0 = topi[t*2],  e1 = topi[t*2+1];
  float w0 = topw[t*2], w1 = topw[t*2+1];
  int d = threadIdx.x * 4;
  u16x4 y0 = *(const u16x4*)(Y + (size_t)s0*DDIM + d);
  u16x4 y1 = *(const u16x4*)(Y + (size_t)s1*DDIM + d);
  f4v c0 = *(const f4v*)(b2 + (size_t)e0*DDIM + d);
  f4v c1 = *(const f4v*)(b2 + (size_t)e1*DDIM + d);
  f4v o;
#pragma unroll
  for (int j = 0; j < 4; j++)
    o[j] = w0*(bf2f(y0[j]) + c0[j]) + w1*(bf2f(y1[j]) + c1[j]);
  *(f4v*)(out + (size_t)t*DDIM + d) = o;
}

extern "C" void kernel_launch(void* const* d_in, const int* in_sizes, int n_in,
                              void* d_out, int out_size, void* d_ws, size_t ws_size,
                              hipStream_t stream) {
  const float* x  = (const float*)d_in[0];
  const float* w1 = (const float*)d_in[1];
  const float* b1 = (const float*)d_in[2];
  const float* w2 = (const float*)d_in[3];
  const float* b2 = (const float*)d_in[4];
  const float* rw = (const float*)d_in[5];
  const float* rb = (const float*)d_in[6];
  float* out = (float*)d_out;

  char* p = (char*)d_ws;
  size_t o = 0;
  auto take = [&](size_t bytes) -> void* {
    void* r = p + o;
    o = (o + bytes + 255) & ~(size_t)255;
    return r;
  };
  int*            counts  = (int*)take(NEXP * 4);
  int*            offsets = (int*)take((NEXP + 1) * 4);
  int*            tlist   = (int*)take(MAXTILES * 4);
  int*            tcount  = (int*)take(4);
  int*            topi    = (int*)take((size_t)NASG * 4);
  float*          topw    = (float*)take((size_t)NASG * 4);
  int*            perm    = (int*)take((size_t)NASG * 4);
  int*            islot   = (int*)take((size_t)NASG * 4);
  unsigned short* w1t     = (unsigned short*)take((size_t)NEXP * FDIM * DDIM * 2);
  unsigned short* xb      = (unsigned short*)take((size_t)TTOK * DDIM * 2);
  unsigned short* w2t     = (unsigned short*)take((size_t)NEXP * DDIM * FDIM * 2);
  unsigned short* H       = (unsigned short*)take((size_t)NASG * FDIM * 2);
  // Y (bf16, 32 MiB) aliases w1t (dead after gemm1, 64 MiB)
  unsigned short* Y       = w1t;

  if (o > ws_size) {   // workspace insufficient: fail visibly (zeros)
    hipMemsetAsync(d_out, 0, (size_t)out_size * 4, stream);
    return;
  }

  hipMemsetAsync(counts, 0, NEXP * 4, stream);

  const int T1B = NEXP*(DDIM/128)*(FDIM/128);       // 2048 w1 transpose tiles
  const int G1B = (MAXTILES-1)*(FDIM/128);          // 4320 gemm1 blocks
  const int T2B = NEXP*(FDIM/64)*(DDIM/64);         // 8192 w2 transpose tiles

  prep_kernel<<<PRB + T1B, 512, 0, stream>>>(x, rw, rb, topi, topw, counts, xb, w1, w1t);
  permbuild_kernel<<<1, 256, 0, stream>>>(topi, counts, offsets, perm, islot, tlist, tcount);
  gemm128<DDIM, FDIM, true , true ><<<G1B + T2B, 256, 0, stream>>>(
      xb, w1t, b1, perm, offsets, tlist, tcount, w2, w2t, (void*)H);
  gemm128<FDIM, DDIM, false, false><<<(MAXTILES-1)*(DDIM/128), 256, 0, stream>>>(
      H, w2t, nullptr, perm, offsets, tlist, tcount, nullptr, nullptr, (void*)Y);
  combine_kernel<<<TTOK, 256, 0, stream>>>(Y, b2, topi, topw, islot, out);
}

// Round 26
// 521.363 us; speedup vs baseline: 1.4093x; 1.3191x over previous
//
#include <hip/hip_runtime.h>
#include <stdint.h>
#include <math.h>

#define TTOK 8192
#define DDIM 1024
#define FDIM 4096
#define NEXP 8
#define NASG (TTOK*2)
#define MAXTILES 136   // sum ceil(n_e/128) <= 128 + 7
#define PRB (TTOK/8)   // 1024 router blocks @ 512 threads (8 tokens/block)

typedef __attribute__((ext_vector_type(8))) short bf16x8;
typedef __attribute__((ext_vector_type(4))) float f32x4;
typedef __attribute__((ext_vector_type(4))) float f4v;
typedef __attribute__((ext_vector_type(4))) unsigned short u16x4;
typedef __attribute__((ext_vector_type(8))) unsigned short u16x8;

__device__ __forceinline__ unsigned short f2bf(float f) {
  union { float f; unsigned int u; } v; v.f = f;
  unsigned int u = v.u;
  u += 0x7fffu + ((u >> 16) & 1u);   // round-to-nearest-even
  return (unsigned short)(u >> 16);
}

__device__ __forceinline__ float bf2f(unsigned short s) {
  union { unsigned int u; float f; } v; v.u = (unsigned int)s << 16;
  return v.f;
}

__device__ __forceinline__ void gload16(const void* g, void* l) {
  __builtin_amdgcn_global_load_lds(
    (__attribute__((address_space(1))) unsigned int*)(uintptr_t)g,
    (__attribute__((address_space(3))) unsigned int*)(uintptr_t)l,
    16, 0, 0);
}

// ===== prep: router (blocks 0..PRB) + w1 transpose (rest), co-scheduled =====
// router: one wave per token, fp64 accumulate, vectorized NT loads, emits xb.
// w1 transpose: 128x128 tiles, XOR-swizzled 64KB LDS, NT f32 reads (keeps the
// bf16 output L3-resident for gemm1), u16x8 stores.
__global__ __launch_bounds__(512) void prep_kernel(
    const float* __restrict__ x, const float* __restrict__ rw,
    const float* __restrict__ rb, int* __restrict__ topi,
    float* __restrict__ topw,
    unsigned short* __restrict__ xb,
    const float* __restrict__ w1, unsigned short* __restrict__ w1t)
{
  __shared__ float lds[128*128];   // 64 KB (transpose branch only)
  int blk = blockIdx.x;
  if (blk < PRB) {
    // ---------------- router ----------------
    int wave = threadIdx.x >> 6;
    int lane = threadIdx.x & 63;
    int t = blk * 8 + wave;
    if (t >= TTOK) return;
    double acc[8];
#pragma unroll
    for (int e = 0; e < 8; e++) acc[e] = 0.0;
    const float* xr = x + (size_t)t * DDIM;
    unsigned short* xbr = xb + (size_t)t * DDIM;
#pragma unroll
    for (int i = 0; i < DDIM/256; i++) {
      int d4 = i*256 + lane*4;
      f4v xv4 = __builtin_nontemporal_load((const f4v*)(xr + d4));  // read-once
      u16x4 ov;
      ov[0] = f2bf(xv4[0]); ov[1] = f2bf(xv4[1]);
      ov[2] = f2bf(xv4[2]); ov[3] = f2bf(xv4[3]);
      *(u16x4*)(xbr + d4) = ov;
#pragma unroll
      for (int j = 0; j < 4; j++) {
        double xv = (double)xv4[j];
        const float* rwr = rw + (size_t)(d4 + j) * 8;
        f4v r0 = *(const f4v*)(rwr);
        f4v r1 = *(const f4v*)(rwr + 4);
        acc[0] += xv * (double)r0[0];
        acc[1] += xv * (double)r0[1];
        acc[2] += xv * (double)r0[2];
        acc[3] += xv * (double)r0[3];
        acc[4] += xv * (double)r1[0];
        acc[5] += xv * (double)r1[1];
        acc[6] += xv * (double)r1[2];
        acc[7] += xv * (double)r1[3];
      }
    }
#pragma unroll
    for (int e = 0; e < 8; e++) {
      for (int off = 32; off >= 1; off >>= 1)
        acc[e] += __shfl_xor(acc[e], off);
    }
    if (lane == 0) {
      float lg[8];
#pragma unroll
      for (int e = 0; e < 8; e++) lg[e] = (float)acc[e] + rb[e];
      int i0 = 0;
      for (int e = 1; e < 8; e++) if (lg[e] > lg[i0]) i0 = e;   // ties -> lowest idx
      int i1 = -1;
      for (int e = 0; e < 8; e++) {
        if (e == i0) continue;
        if (i1 < 0 || lg[e] > lg[i1]) i1 = e;
      }
      double z = exp((double)lg[i1] - (double)lg[i0]);
      float w0 = (float)(1.0 / (1.0 + z));
      topi[t*2]   = i0;  topi[t*2+1] = i1;
      topw[t*2]   = w0;  topw[t*2+1] = 1.0f - w0;
    }
    return;
  }
  // ---------------- w1 transpose: [E][DDIM][FDIM] f32 -> [E][FDIM][DDIM] bf16
  int b = blk - PRB;
  const int R = DDIM, C = FDIM;
  const int perMat = (DDIM/128)*(FDIM/128);   // 256
  int tpr = C >> 7;
  int e = b / perMat;
  int rem = b - e*perMat;
  int tr = rem / tpr;
  int tc = rem - tr*tpr;
  int tid = threadIdx.x;
  size_t ibase = (size_t)e*R*C + (size_t)(tr*128)*C + (size_t)(tc*128);
  size_t obase = (size_t)e*R*C + (size_t)(tc*128)*R + (size_t)(tr*128);
  // phase 1: non-temporal float4 loads, 512B contiguous per 32 lanes
#pragma unroll
  for (int i = 0; i < 8; i++) {
    int s = tid + i*512;
    int r = s >> 5;
    int c4 = (s & 31) << 2;
    f4v v = __builtin_nontemporal_load((const f4v*)(w1 + ibase + (size_t)r*C + c4));
    int xr = r & 31;
#pragma unroll
    for (int j = 0; j < 4; j++)
      lds[r*128 + ((c4 + j) ^ xr)] = v[j];
  }
  __syncthreads();
  // phase 2: out[oc][r8..r8+7] via u16x8 (16B) stores, 256B per out-row group
#pragma unroll
  for (int i = 0; i < 4; i++) {
    int s = tid + i*512;
    int oc = s >> 4;
    int r8 = (s & 15) << 3;
    u16x8 o;
#pragma unroll
    for (int j = 0; j < 8; j++) {
      int r = r8 + j;
      o[j] = f2bf(lds[r*128 + (oc ^ (r & 31))]);
    }
    *(u16x8*)(w1t + obase + (size_t)oc*R + r8) = o;
  }
}

// ------ counting sort + compact tile list (single block, self-sufficient) ------
// Totals derived from the in-block histogram scan: no global counts buffer,
// no memset dispatch, no router atomics.
__global__ __launch_bounds__(256) void permbuild_kernel(
    const int* __restrict__ topi,
    int* __restrict__ offsets, int* __restrict__ perm, int* __restrict__ islot,
    int* __restrict__ tlist, int* __restrict__ tcount)
{
  __shared__ int hist[256 * 8];
  __shared__ int offs[NEXP + 1];
  __shared__ int tot[NEXP];
  int tid = threadIdx.x;
  int cnt[8];
#pragma unroll
  for (int e = 0; e < 8; e++) cnt[e] = 0;
  int base = tid * 64;
  for (int i = 0; i < 64; i++) cnt[topi[base + i]]++;
#pragma unroll
  for (int e = 0; e < 8; e++) hist[tid*8 + e] = cnt[e];
  __syncthreads();
  if (tid < 8) {
    int s = 0;
    for (int th = 0; th < 256; th++) { int v = hist[th*8 + tid]; hist[th*8 + tid] = s; s += v; }
    tot[tid] = s;
  }
  __syncthreads();
  if (tid == 0) {
    int s = 0;
    for (int e = 0; e < 8; e++) { offs[e] = s; s += tot[e]; }
    offs[8] = s;
    for (int e = 0; e <= 8; e++) offsets[e] = offs[e];
    int k = 0;
    for (int e = 0; e < 8; e++) {
      int m = (tot[e] + 127) >> 7;
      for (int r = 0; r < m; r++) tlist[k++] = (e << 8) | r;
    }
    tcount[0] = k;
  }
  __syncthreads();
  int pos[8];
#pragma unroll
  for (int e = 0; e < 8; e++) pos[e] = offs[e] + hist[tid*8 + e];
  for (int i = 0; i < 64; i++) {
    int a = base + i;
    int e = topi[a];
    int p = pos[e]++;
    perm[p] = a >> 1;
    islot[a] = p;
  }
}

// ========= 128x128 grouped GEMM, m97-faithful + compact tile list ==========
// r10-verbatim loop, linear decode (id%8 = nt%8 pins each B-panel to one
// XCD's L2 -- measured optimal). Cacheable H/Y stores (r22: NT-H regressed).
// NO __launch_bounds__ (r12) / NO atomics (r18).
// FUSET2: blocks past the gemm range perform the w2 transpose (64x64 tiles)
// -- w2t has no consumer until gemm2, so this hides its BW-bound work under
// gemm1's latency-bound execution (r24: +21us incremental vs +60us serial).

template<int KDIM, int NDIM, bool GELU, bool FUSET2>
__global__ void gemm128(
    const unsigned short* __restrict__ Asrc,
    const unsigned short* __restrict__ Bsrc,
    const float* __restrict__ bias,
    const int* __restrict__ perm,
    const int* __restrict__ offsets,
    const int* __restrict__ tlist,
    const int* __restrict__ tcount,
    const float* __restrict__ w2src,
    unsigned short* __restrict__ w2dst,
    void* __restrict__ Cout)
{
  constexpr int KT = KDIM / 64;
  constexpr int NT = NDIM / 128;
  constexpr int G1B = (MAXTILES-1) * NT;

  __shared__ __align__(16) char smem[32768];   // union: gemm 32KB | transpose 16.6KB

  if constexpr (FUSET2) {
    if (blockIdx.x >= G1B) {
      // ---- w2 transpose tile (64x64 path): [E][FDIM][DDIM] f32
      // -> [E][DDIM][FDIM] bf16. NT loads protect L3 residency of gemm operands.
      float (*tile)[65] = (float(*)[65])smem;
      int b = blockIdx.x - G1B;
      const int R = FDIM, C = DDIM;
      const int tilesPerRow = C >> 6;              // 16
      const int tilesPerMat = (R >> 6) * tilesPerRow;  // 1024
      int e = b / tilesPerMat;
      int rem = b - e * tilesPerMat;
      int tr = rem / tilesPerRow;
      int tc = rem - tr * tilesPerRow;
      int tid = threadIdx.x;
      size_t ibase = (size_t)e*R*C + ((size_t)tr*64)*C + (size_t)tc*64;
#pragma unroll
      for (int i = 0; i < 4; i++) {
        int idx = tid + i*256;          // 0..1023
        int r  = idx >> 4;              // input row 0..63
        int c4 = (idx & 15) * 4;        // input col group
        f4v v = __builtin_nontemporal_load((const f4v*)(w2src + ibase + (size_t)r*C + c4));
        tile[r][c4+0] = v[0];
        tile[r][c4+1] = v[1];
        tile[r][c4+2] = v[2];
        tile[r][c4+3] = v[3];
      }
      __syncthreads();
      size_t obase = (size_t)e*R*C + ((size_t)tc*64)*R + (size_t)tr*64;
#pragma unroll
      for (int i = 0; i < 4; i++) {
        int idx = tid + i*256;
        int r  = idx >> 4;              // output row 0..63
        int c4 = (idx & 15) * 4;        // output col group
        u16x4 v;
        v[0] = f2bf(tile[c4+0][r]);
        v[1] = f2bf(tile[c4+1][r]);
        v[2] = f2bf(tile[c4+2][r]);
        v[3] = f2bf(tile[c4+3][r]);
        *(u16x4*)(w2dst + obase + (size_t)r*R + c4) = v;
      }
      return;
    }
  }

  int b = blockIdx.x;
  int ti = b / NT;
  int nt = b - ti * NT;
  if (ti >= tcount[0]) return;
  int code = tlist[ti];
  int e = code >> 8;
  int rt = code & 255;
  int off = offsets[e];
  int n_e = offsets[e+1] - off;

  char* ldsA = smem;            // A: 128 rows x 128B
  char* ldsB = smem + 16384;    // B: 128 rows x 128B

  int tid = threadIdx.x;
  int lane = tid & 63;
  int wid = tid >> 6;          // 0..3
  int wr = wid >> 1;           // 0..1 (M strip)
  int wc = wid & 1;            // 0..1 (N strip)
  int tb0 = (lane >> 4) * 16;
  int rA = wr*64 + (lane & 15);
  int rB = wc*64 + (lane & 15);
  int xa  = (rA & 7) << 4;
  int xbw = (rB & 7) << 4;
  int aks0 = rA*128 + ( tb0       ^ xa);
  int aks1 = rA*128 + ((64 + tb0) ^ xa);
  int bks0 = rB*128 + ( tb0       ^ xbw);
  int bks1 = rB*128 + ((64 + tb0) ^ xbw);

  // staging: 4 A-slots + 4 B-slots per thread (1024 slots = 128 rows x 8 chunks)
  const char* srcA[4];
  const char* srcB[4];
#pragma unroll
  for (int i = 0; i < 4; i++) {
    int slot = tid + i*256;
    int r = slot >> 3;
    int kc = (slot & 7) ^ (r & 7);   // inverse swizzle on global k-chunk
    int g = off + rt*128 + r;
    if (g > NASG-1) g = NASG-1;
    size_t ar = GELU ? (size_t)perm[g] : (size_t)g;
    srcA[i] = (const char*)Asrc + (ar * KDIM + (size_t)kc*8) * 2;
    int col = nt*128 + r;
    srcB[i] = (const char*)Bsrc + (((size_t)e*NDIM + col) * KDIM + (size_t)kc*8) * 2;
  }
  int dstOff = tid * 16;

  f32x4 acc[4][4];
#pragma unroll
  for (int m = 0; m < 4; m++)
#pragma unroll
    for (int n = 0; n < 4; n++) acc[m][n] = (f32x4){0.f,0.f,0.f,0.f};

#pragma unroll 1
  for (int kt = 0; kt < KT; ++kt) {
    __syncthreads();   // previous compute done before overwrite
#pragma unroll
    for (int i = 0; i < 4; i++) {
      gload16(srcA[i] + (size_t)kt*128, ldsA + dstOff + i*4096);
      gload16(srcB[i] + (size_t)kt*128, ldsB + dstOff + i*4096);
    }
    __syncthreads();   // compiler-inserted vmcnt(0) drain: tile ready
#pragma unroll
    for (int ks = 0; ks < 2; ks++) {
      int ao = ks ? aks1 : aks0;
      int bo = ks ? bks1 : bks0;
      bf16x8 a[4], bb[4];
#pragma unroll
      for (int mi = 0; mi < 4; mi++) a[mi]  = *(const bf16x8*)(ldsA + mi*2048 + ao);
#pragma unroll
      for (int ni = 0; ni < 4; ni++) bb[ni] = *(const bf16x8*)(ldsB + ni*2048 + bo);
#pragma unroll
      for (int mi = 0; mi < 4; mi++)
#pragma unroll
        for (int ni = 0; ni < 4; ni++)
          acc[mi][ni] = __builtin_amdgcn_mfma_f32_16x16x32_bf16(a[mi], bb[ni], acc[mi][ni], 0, 0, 0);
    }
  }

  // epilogue
  int rq = (lane >> 4) * 4;
  int lc = lane & 15;
  if (GELU) {
    unsigned short* H = (unsigned short*)Cout;
#pragma unroll
    for (int mi = 0; mi < 4; mi++)
#pragma unroll
      for (int j = 0; j < 4; j++) {
        int sl = rt*128 + wr*64 + mi*16 + rq + j;
        if (sl < n_e) {
          size_t hrow = (size_t)(off + sl) * NDIM;
#pragma unroll
          for (int ni = 0; ni < 4; ni++) {
            int col = nt*128 + wc*64 + ni*16 + lc;
            float v = acc[mi][ni][j] + bias[e*NDIM + col];
            float g = 0.5f * v * (1.0f + erff(v * 0.70710678118654752f));
            H[hrow + col] = f2bf(g);
          }
        }
      }
  } else {
    unsigned short* Y = (unsigned short*)Cout;   // bf16 partial outputs
#pragma unroll
    for (int mi = 0; mi < 4; mi++)
#pragma unroll
      for (int j = 0; j < 4; j++) {
        int sl = rt*128 + wr*64 + mi*16 + rq + j;
        if (sl < n_e) {
          size_t yrow = (size_t)(off + sl) * NDIM;
#pragma unroll
          for (int ni = 0; ni < 4; ni++) {
            int col = nt*128 + wc*64 + ni*16 + lc;
            Y[yrow + col] = f2bf(acc[mi][ni][j]);
          }
        }
      }
  }
}

// ---------- combine: out[t] = sum_k w_k * (Y[slot_k] + b2[e_k]) ----------
__global__ __launch_bounds__(256) void combine_kernel(
    const unsigned short* __restrict__ Y, const float* __restrict__ b2,
    const int* __restrict__ topi, const float* __restrict__ topw,
    const int* __restrict__ islot, float* __restrict__ out)
{
  int t = blockIdx.x;
  int s0 = islot[t*2], s1 = islot[t*2+1];
  int e0 = topi[t*2],  e1 = topi[t*2+1];
  float w0 = topw[t*2], w1 = topw[t*2+1];
  int d = threadIdx.x * 4;
  u16x4 y0 = *(const u16x4*)(Y + (size_t)s0*DDIM + d);
  u16x4 y1 = *(const u16x4*)(Y + (size_t)s1*DDIM + d);
  f4v c0 = *(const f4v*)(b2 + (size_t)e0*DDIM + d);
  f4v c1 = *(const f4v*)(b2 + (size_t)e1*DDIM + d);
  f4v o;
#pragma unroll
  for (int j = 0; j < 4; j++)
    o[j] = w0*(bf2f(y0[j]) + c0[j]) + w1*(bf2f(y1[j]) + c1[j]);
  *(f4v*)(out + (size_t)t*DDIM + d) = o;
}

extern "C" void kernel_launch(void* const* d_in, const int* in_sizes, int n_in,
                              void* d_out, int out_size, void* d_ws, size_t ws_size,
                              hipStream_t stream) {
  const float* x  = (const float*)d_in[0];
  const float* w1 = (const float*)d_in[1];
  const float* b1 = (const float*)d_in[2];
  const float* w2 = (const float*)d_in[3];
  const float* b2 = (const float*)d_in[4];
  const float* rw = (const float*)d_in[5];
  const float* rb = (const float*)d_in[6];
  float* out = (float*)d_out;

  char* p = (char*)d_ws;
  size_t o = 0;
  auto take = [&](size_t bytes) -> void* {
    void* r = p + o;
    o = (o + bytes + 255) & ~(size_t)255;
    return r;
  };
  int*            offsets = (int*)take((NEXP + 1) * 4);
  int*            tlist   = (int*)take(MAXTILES * 4);
  int*            tcount  = (int*)take(4);
  int*            topi    = (int*)take((size_t)NASG * 4);
  float*          topw    = (float*)take((size_t)NASG * 4);
  int*            perm    = (int*)take((size_t)NASG * 4);
  int*            islot   = (int*)take((size_t)NASG * 4);
  unsigned short* w1t     = (unsigned short*)take((size_t)NEXP * FDIM * DDIM * 2);
  unsigned short* xb      = (unsigned short*)take((size_t)TTOK * DDIM * 2);
  unsigned short* w2t     = (unsigned short*)take((size_t)NEXP * DDIM * FDIM * 2);
  unsigned short* H       = (unsigned short*)take((size_t)NASG * FDIM * 2);
  // Y (bf16, 32 MiB) aliases w1t (dead after gemm1, 64 MiB)
  unsigned short* Y       = w1t;

  if (o > ws_size) {   // workspace insufficient: fail visibly (zeros)
    hipMemsetAsync(d_out, 0, (size_t)out_size * 4, stream);
    return;
  }

  const int T1B = NEXP*(DDIM/128)*(FDIM/128);       // 2048 w1 transpose tiles
  const int G1B = (MAXTILES-1)*(FDIM/128);          // 4320 gemm1 blocks
  const int T2B = NEXP*(FDIM/64)*(DDIM/64);         // 8192 w2 transpose tiles

  prep_kernel<<<PRB + T1B, 512, 0, stream>>>(x, rw, rb, topi, topw, xb, w1, w1t);
  permbuild_kernel<<<1, 256, 0, stream>>>(topi, offsets, perm, islot, tlist, tcount);
  gemm128<DDIM, FDIM, true , true ><<<G1B + T2B, 256, 0, stream>>>(
      xb, w1t, b1, perm, offsets, tlist, tcount, w2, w2t, (void*)H);
  gemm128<FDIM, DDIM, false, false><<<(MAXTILES-1)*(DDIM/128), 256, 0, stream>>>(
      H, w2t, nullptr, perm, offsets, tlist, tcount, nullptr, nullptr, (void*)Y);
  combine_kernel<<<TTOK, 256, 0, stream>>>(Y, b2, topi, topw, islot, out);
}

// Round 27
// 518.504 us; speedup vs baseline: 1.4171x; 1.0055x over previous
//
#include <hip/hip_runtime.h>
#include <stdint.h>
#include <math.h>

#define TTOK 8192
#define DDIM 1024
#define FDIM 4096
#define NEXP 8
#define NASG (TTOK*2)
#define MAXTILES 136   // sum ceil(n_e/128) <= 128 + 7
#define PRB (TTOK/8)   // 1024 router blocks @ 512 threads (8 tokens/block)

typedef __attribute__((ext_vector_type(8))) short bf16x8;
typedef __attribute__((ext_vector_type(4))) float f32x4;
typedef __attribute__((ext_vector_type(4))) float f4v;
typedef __attribute__((ext_vector_type(4))) unsigned short u16x4;
typedef __attribute__((ext_vector_type(8))) unsigned short u16x8;

__device__ __forceinline__ unsigned short f2bf(float f) {
  union { float f; unsigned int u; } v; v.f = f;
  unsigned int u = v.u;
  u += 0x7fffu + ((u >> 16) & 1u);   // round-to-nearest-even
  return (unsigned short)(u >> 16);
}

__device__ __forceinline__ float bf2f(unsigned short s) {
  union { unsigned int u; float f; } v; v.u = (unsigned int)s << 16;
  return v.f;
}

__device__ __forceinline__ void gload16(const void* g, void* l) {
  __builtin_amdgcn_global_load_lds(
    (__attribute__((address_space(1))) unsigned int*)(uintptr_t)g,
    (__attribute__((address_space(3))) unsigned int*)(uintptr_t)l,
    16, 0, 0);
}

// ===== prep: router (blocks 0..PRB) + w1 transpose (rest), co-scheduled =====
// router: one wave per token, fp64 accumulate, vectorized NT loads, emits xb.
// w1 transpose: 128x128 tiles, XOR-swizzled 64KB LDS, NT f32 reads (keeps the
// bf16 output L3-resident for gemm1), u16x8 stores. No atomics, no counts.
__global__ __launch_bounds__(512) void prep_kernel(
    const float* __restrict__ x, const float* __restrict__ rw,
    const float* __restrict__ rb, int* __restrict__ topi,
    float* __restrict__ topw,
    unsigned short* __restrict__ xb,
    const float* __restrict__ w1, unsigned short* __restrict__ w1t)
{
  __shared__ float lds[128*128];   // 64 KB (transpose branch only)
  int blk = blockIdx.x;
  if (blk < PRB) {
    // ---------------- router ----------------
    int wave = threadIdx.x >> 6;
    int lane = threadIdx.x & 63;
    int t = blk * 8 + wave;
    if (t >= TTOK) return;
    double acc[8];
#pragma unroll
    for (int e = 0; e < 8; e++) acc[e] = 0.0;
    const float* xr = x + (size_t)t * DDIM;
    unsigned short* xbr = xb + (size_t)t * DDIM;
#pragma unroll
    for (int i = 0; i < DDIM/256; i++) {
      int d4 = i*256 + lane*4;
      f4v xv4 = __builtin_nontemporal_load((const f4v*)(xr + d4));  // read-once
      u16x4 ov;
      ov[0] = f2bf(xv4[0]); ov[1] = f2bf(xv4[1]);
      ov[2] = f2bf(xv4[2]); ov[3] = f2bf(xv4[3]);
      *(u16x4*)(xbr + d4) = ov;
#pragma unroll
      for (int j = 0; j < 4; j++) {
        double xv = (double)xv4[j];
        const float* rwr = rw + (size_t)(d4 + j) * 8;
        f4v r0 = *(const f4v*)(rwr);
        f4v r1 = *(const f4v*)(rwr + 4);
        acc[0] += xv * (double)r0[0];
        acc[1] += xv * (double)r0[1];
        acc[2] += xv * (double)r0[2];
        acc[3] += xv * (double)r0[3];
        acc[4] += xv * (double)r1[0];
        acc[5] += xv * (double)r1[1];
        acc[6] += xv * (double)r1[2];
        acc[7] += xv * (double)r1[3];
      }
    }
#pragma unroll
    for (int e = 0; e < 8; e++) {
      for (int off = 32; off >= 1; off >>= 1)
        acc[e] += __shfl_xor(acc[e], off);
    }
    if (lane == 0) {
      float lg[8];
#pragma unroll
      for (int e = 0; e < 8; e++) lg[e] = (float)acc[e] + rb[e];
      int i0 = 0;
      for (int e = 1; e < 8; e++) if (lg[e] > lg[i0]) i0 = e;   // ties -> lowest idx
      int i1 = -1;
      for (int e = 0; e < 8; e++) {
        if (e == i0) continue;
        if (i1 < 0 || lg[e] > lg[i1]) i1 = e;
      }
      double z = exp((double)lg[i1] - (double)lg[i0]);
      float w0 = (float)(1.0 / (1.0 + z));
      topi[t*2]   = i0;  topi[t*2+1] = i1;
      topw[t*2]   = w0;  topw[t*2+1] = 1.0f - w0;
    }
    return;
  }
  // ---------------- w1 transpose: [E][DDIM][FDIM] f32 -> [E][FDIM][DDIM] bf16
  int b = blk - PRB;
  const int R = DDIM, C = FDIM;
  const int perMat = (DDIM/128)*(FDIM/128);   // 256
  int tpr = C >> 7;
  int e = b / perMat;
  int rem = b - e*perMat;
  int tr = rem / tpr;
  int tc = rem - tr*tpr;
  int tid = threadIdx.x;
  size_t ibase = (size_t)e*R*C + (size_t)(tr*128)*C + (size_t)(tc*128);
  size_t obase = (size_t)e*R*C + (size_t)(tc*128)*R + (size_t)(tr*128);
  // phase 1: non-temporal float4 loads, 512B contiguous per 32 lanes
#pragma unroll
  for (int i = 0; i < 8; i++) {
    int s = tid + i*512;
    int r = s >> 5;
    int c4 = (s & 31) << 2;
    f4v v = __builtin_nontemporal_load((const f4v*)(w1 + ibase + (size_t)r*C + c4));
    int xr = r & 31;
#pragma unroll
    for (int j = 0; j < 4; j++)
      lds[r*128 + ((c4 + j) ^ xr)] = v[j];
  }
  __syncthreads();
  // phase 2: out[oc][r8..r8+7] via u16x8 (16B) stores, 256B per out-row group
#pragma unroll
  for (int i = 0; i < 4; i++) {
    int s = tid + i*512;
    int oc = s >> 4;
    int r8 = (s & 15) << 3;
    u16x8 o;
#pragma unroll
    for (int j = 0; j < 8; j++) {
      int r = r8 + j;
      o[j] = f2bf(lds[r*128 + (oc ^ (r & 31))]);
    }
    *(u16x8*)(w1t + obase + (size_t)oc*R + r8) = o;
  }
}

// ------ counting sort + compact tile list (single block, self-sufficient) ------
// Totals derived from the in-block histogram scan: no global counts buffer,
// no memset dispatch, no router atomics (r26: eliminated graph serialization,
// -166us total).
__global__ __launch_bounds__(256) void permbuild_kernel(
    const int* __restrict__ topi,
    int* __restrict__ offsets, int* __restrict__ perm, int* __restrict__ islot,
    int* __restrict__ tlist, int* __restrict__ tcount)
{
  __shared__ int hist[256 * 8];
  __shared__ int offs[NEXP + 1];
  __shared__ int tot[NEXP];
  int tid = threadIdx.x;
  int cnt[8];
#pragma unroll
  for (int e = 0; e < 8; e++) cnt[e] = 0;
  int base = tid * 64;
  for (int i = 0; i < 64; i++) cnt[topi[base + i]]++;
#pragma unroll
  for (int e = 0; e < 8; e++) hist[tid*8 + e] = cnt[e];
  __syncthreads();
  if (tid < 8) {
    int s = 0;
    for (int th = 0; th < 256; th++) { int v = hist[th*8 + tid]; hist[th*8 + tid] = s; s += v; }
    tot[tid] = s;
  }
  __syncthreads();
  if (tid == 0) {
    int s = 0;
    for (int e = 0; e < 8; e++) { offs[e] = s; s += tot[e]; }
    offs[8] = s;
    for (int e = 0; e <= 8; e++) offsets[e] = offs[e];
    int k = 0;
    for (int e = 0; e < 8; e++) {
      int m = (tot[e] + 127) >> 7;
      for (int r = 0; r < m; r++) tlist[k++] = (e << 8) | r;
    }
    tcount[0] = k;
  }
  __syncthreads();
  int pos[8];
#pragma unroll
  for (int e = 0; e < 8; e++) pos[e] = offs[e] + hist[tid*8 + e];
  for (int i = 0; i < 64; i++) {
    int a = base + i;
    int e = topi[a];
    int p = pos[e]++;
    perm[p] = a >> 1;
    islot[a] = p;
  }
}

// ========= 128x128 grouped GEMM, m97-faithful + compact tile list ==========
// r10-verbatim loop, linear decode (id%8 = nt%8 pins each B-panel to one
// XCD's L2 -- measured optimal). Cacheable H/Y stores (r22: NT-H regressed).
// NO __launch_bounds__ (r12) / NO atomics (r18).
// FUSET2: blocks past the gemm range perform the w2 transpose (64x64 tiles)
// -- w2t has no consumer until gemm2, so this hides its BW-bound work under
// gemm1's latency-bound execution (r24: +21us incremental vs +60us serial).

template<int KDIM, int NDIM, bool GELU, bool FUSET2>
__global__ void gemm128(
    const unsigned short* __restrict__ Asrc,
    const unsigned short* __restrict__ Bsrc,
    const float* __restrict__ bias,
    const int* __restrict__ perm,
    const int* __restrict__ offsets,
    const int* __restrict__ tlist,
    const int* __restrict__ tcount,
    const float* __restrict__ w2src,
    unsigned short* __restrict__ w2dst,
    void* __restrict__ Cout)
{
  constexpr int KT = KDIM / 64;
  constexpr int NT = NDIM / 128;
  constexpr int G1B = (MAXTILES-1) * NT;

  __shared__ __align__(16) char smem[32768];   // union: gemm 32KB | transpose 16.6KB

  if constexpr (FUSET2) {
    if (blockIdx.x >= G1B) {
      // ---- w2 transpose tile (64x64 path): [E][FDIM][DDIM] f32
      // -> [E][DDIM][FDIM] bf16. NT loads protect L3 residency of gemm operands.
      float (*tile)[65] = (float(*)[65])smem;
      int b = blockIdx.x - G1B;
      const int R = FDIM, C = DDIM;
      const int tilesPerRow = C >> 6;              // 16
      const int tilesPerMat = (R >> 6) * tilesPerRow;  // 1024
      int e = b / tilesPerMat;
      int rem = b - e * tilesPerMat;
      int tr = rem / tilesPerRow;
      int tc = rem - tr * tilesPerRow;
      int tid = threadIdx.x;
      size_t ibase = (size_t)e*R*C + ((size_t)tr*64)*C + (size_t)tc*64;
#pragma unroll
      for (int i = 0; i < 4; i++) {
        int idx = tid + i*256;          // 0..1023
        int r  = idx >> 4;              // input row 0..63
        int c4 = (idx & 15) * 4;        // input col group
        f4v v = __builtin_nontemporal_load((const f4v*)(w2src + ibase + (size_t)r*C + c4));
        tile[r][c4+0] = v[0];
        tile[r][c4+1] = v[1];
        tile[r][c4+2] = v[2];
        tile[r][c4+3] = v[3];
      }
      __syncthreads();
      size_t obase = (size_t)e*R*C + ((size_t)tc*64)*R + (size_t)tr*64;
#pragma unroll
      for (int i = 0; i < 4; i++) {
        int idx = tid + i*256;
        int r  = idx >> 4;              // output row 0..63
        int c4 = (idx & 15) * 4;        // output col group
        u16x4 v;
        v[0] = f2bf(tile[c4+0][r]);
        v[1] = f2bf(tile[c4+1][r]);
        v[2] = f2bf(tile[c4+2][r]);
        v[3] = f2bf(tile[c4+3][r]);
        *(u16x4*)(w2dst + obase + (size_t)r*R + c4) = v;
      }
      return;
    }
  }

  int b = blockIdx.x;
  int ti = b / NT;
  int nt = b - ti * NT;
  if (ti >= tcount[0]) return;
  int code = tlist[ti];
  int e = code >> 8;
  int rt = code & 255;
  int off = offsets[e];
  int n_e = offsets[e+1] - off;

  char* ldsA = smem;            // A: 128 rows x 128B
  char* ldsB = smem + 16384;    // B: 128 rows x 128B

  int tid = threadIdx.x;
  int lane = tid & 63;
  int wid = tid >> 6;          // 0..3
  int wr = wid >> 1;           // 0..1 (M strip)
  int wc = wid & 1;            // 0..1 (N strip)
  int tb0 = (lane >> 4) * 16;
  int rA = wr*64 + (lane & 15);
  int rB = wc*64 + (lane & 15);
  int xa  = (rA & 7) << 4;
  int xbw = (rB & 7) << 4;
  int aks0 = rA*128 + ( tb0       ^ xa);
  int aks1 = rA*128 + ((64 + tb0) ^ xa);
  int bks0 = rB*128 + ( tb0       ^ xbw);
  int bks1 = rB*128 + ((64 + tb0) ^ xbw);

  // staging: 4 A-slots + 4 B-slots per thread (1024 slots = 128 rows x 8 chunks)
  const char* srcA[4];
  const char* srcB[4];
#pragma unroll
  for (int i = 0; i < 4; i++) {
    int slot = tid + i*256;
    int r = slot >> 3;
    int kc = (slot & 7) ^ (r & 7);   // inverse swizzle on global k-chunk
    int g = off + rt*128 + r;
    if (g > NASG-1) g = NASG-1;
    size_t ar = GELU ? (size_t)perm[g] : (size_t)g;
    srcA[i] = (const char*)Asrc + (ar * KDIM + (size_t)kc*8) * 2;
    int col = nt*128 + r;
    srcB[i] = (const char*)Bsrc + (((size_t)e*NDIM + col) * KDIM + (size_t)kc*8) * 2;
  }
  int dstOff = tid * 16;

  f32x4 acc[4][4];
#pragma unroll
  for (int m = 0; m < 4; m++)
#pragma unroll
    for (int n = 0; n < 4; n++) acc[m][n] = (f32x4){0.f,0.f,0.f,0.f};

#pragma unroll 1
  for (int kt = 0; kt < KT; ++kt) {
    __syncthreads();   // previous compute done before overwrite
#pragma unroll
    for (int i = 0; i < 4; i++) {
      gload16(srcA[i] + (size_t)kt*128, ldsA + dstOff + i*4096);
      gload16(srcB[i] + (size_t)kt*128, ldsB + dstOff + i*4096);
    }
    __syncthreads();   // compiler-inserted vmcnt(0) drain: tile ready
#pragma unroll
    for (int ks = 0; ks < 2; ks++) {
      int ao = ks ? aks1 : aks0;
      int bo = ks ? bks1 : bks0;
      bf16x8 a[4], bb[4];
#pragma unroll
      for (int mi = 0; mi < 4; mi++) a[mi]  = *(const bf16x8*)(ldsA + mi*2048 + ao);
#pragma unroll
      for (int ni = 0; ni < 4; ni++) bb[ni] = *(const bf16x8*)(ldsB + ni*2048 + bo);
#pragma unroll
      for (int mi = 0; mi < 4; mi++)
#pragma unroll
        for (int ni = 0; ni < 4; ni++)
          acc[mi][ni] = __builtin_amdgcn_mfma_f32_16x16x32_bf16(a[mi], bb[ni], acc[mi][ni], 0, 0, 0);
    }
  }

  // epilogue
  int rq = (lane >> 4) * 4;
  int lc = lane & 15;
  if (GELU) {
    unsigned short* H = (unsigned short*)Cout;
#pragma unroll
    for (int mi = 0; mi < 4; mi++)
#pragma unroll
      for (int j = 0; j < 4; j++) {
        int sl = rt*128 + wr*64 + mi*16 + rq + j;
        if (sl < n_e) {
          size_t hrow = (size_t)(off + sl) * NDIM;
#pragma unroll
          for (int ni = 0; ni < 4; ni++) {
            int col = nt*128 + wc*64 + ni*16 + lc;
            float v = acc[mi][ni][j] + bias[e*NDIM + col];
            float g = 0.5f * v * (1.0f + erff(v * 0.70710678118654752f));
            H[hrow + col] = f2bf(g);
          }
        }
      }
  } else {
    unsigned short* Y = (unsigned short*)Cout;   // bf16 partial outputs
#pragma unroll
    for (int mi = 0; mi < 4; mi++)
#pragma unroll
      for (int j = 0; j < 4; j++) {
        int sl = rt*128 + wr*64 + mi*16 + rq + j;
        if (sl < n_e) {
          size_t yrow = (size_t)(off + sl) * NDIM;
#pragma unroll
          for (int ni = 0; ni < 4; ni++) {
            int col = nt*128 + wc*64 + ni*16 + lc;
            Y[yrow + col] = f2bf(acc[mi][ni][j]);
          }
        }
      }
  }
}

// ---------- combine: out[t] = sum_k w_k * (Y[slot_k] + b2[e_k]) ----------
__global__ __launch_bounds__(256) void combine_kernel(
    const unsigned short* __restrict__ Y, const float* __restrict__ b2,
    const int* __restrict__ topi, const float* __restrict__ topw,
    const int* __restrict__ islot, float* __restrict__ out)
{
  int t = blockIdx.x;
  int s0 = islot[t*2], s1 = islot[t*2+1];
  int e0 = topi[t*2],  e1 = topi[t*2+1];
  float w0 = topw[t*2], w1 = topw[t*2+1];
  int d = threadIdx.x * 4;
  u16x4 y0 = *(const u16x4*)(Y + (size_t)s0*DDIM + d);
  u16x4 y1 = *(const u16x4*)(Y + (size_t)s1*DDIM + d);
  f4v c0 = *(const f4v*)(b2 + (size_t)e0*DDIM + d);
  f4v c1 = *(const f4v*)(b2 + (size_t)e1*DDIM + d);
  f4v o;
#pragma unroll
  for (int j = 0; j < 4; j++)
    o[j] = w0*(bf2f(y0[j]) + c0[j]) + w1*(bf2f(y1[j]) + c1[j]);
  *(f4v*)(out + (size_t)t*DDIM + d) = o;
}

extern "C" void kernel_launch(void* const* d_in, const int* in_sizes, int n_in,
                              void* d_out, int out_size, void* d_ws, size_t ws_size,
                              hipStream_t stream) {
  const float* x  = (const float*)d_in[0];
  const float* w1 = (const float*)d_in[1];
  const float* b1 = (const float*)d_in[2];
  const float* w2 = (const float*)d_in[3];
  const float* b2 = (const float*)d_in[4];
  const float* rw = (const float*)d_in[5];
  const float* rb = (const float*)d_in[6];
  float* out = (float*)d_out;

  char* p = (char*)d_ws;
  size_t o = 0;
  auto take = [&](size_t bytes) -> void* {
    void* r = p + o;
    o = (o + bytes + 255) & ~(size_t)255;
    return r;
  };
  int*            offsets = (int*)take((NEXP + 1) * 4);
  int*            tlist   = (int*)take(MAXTILES * 4);
  int*            tcount  = (int*)take(4);
  int*            topi    = (int*)take((size_t)NASG * 4);
  float*          topw    = (float*)take((size_t)NASG * 4);
  int*            perm    = (int*)take((size_t)NASG * 4);
  int*            islot   = (int*)take((size_t)NASG * 4);
  unsigned short* w1t     = (unsigned short*)take((size_t)NEXP * FDIM * DDIM * 2);
  unsigned short* xb      = (unsigned short*)take((size_t)TTOK * DDIM * 2);
  unsigned short* w2t     = (unsigned short*)take((size_t)NEXP * DDIM * FDIM * 2);
  unsigned short* H       = (unsigned short*)take((size_t)NASG * FDIM * 2);
  // Y (bf16, 32 MiB) aliases w1t (dead after gemm1, 64 MiB)
  unsigned short* Y       = w1t;

  if (o > ws_size) {   // workspace insufficient: fail visibly (zeros)
    hipMemsetAsync(d_out, 0, (size_t)out_size * 4, stream);
    return;
  }

  const int T1B = NEXP*(DDIM/128)*(FDIM/128);       // 2048 w1 transpose tiles
  const int G1B = (MAXTILES-1)*(FDIM/128);          // 4320 gemm1 blocks
  const int T2B = NEXP*(FDIM/64)*(DDIM/64);         // 8192 w2 transpose tiles

  prep_kernel<<<PRB + T1B, 512, 0, stream>>>(x, rw, rb, topi, topw, xb, w1, w1t);
  permbuild_kernel<<<1, 256, 0, stream>>>(topi, offsets, perm, islot, tlist, tcount);
  gemm128<DDIM, FDIM, true , true ><<<G1B + T2B, 256, 0, stream>>>(
      xb, w1t, b1, perm, offsets, tlist, tcount, w2, w2t, (void*)H);
  gemm128<FDIM, DDIM, false, false><<<(MAXTILES-1)*(DDIM/128), 256, 0, stream>>>(
      H, w2t, nullptr, perm, offsets, tlist, tcount, nullptr, nullptr, (void*)Y);
  combine_kernel<<<TTOK, 256, 0, stream>>>(Y, b2, topi, topw, islot, out);
}